// Round 2
// baseline (565.568 us; speedup 1.0000x reference)
//
#include <hip/hip_runtime.h>
#include <hip/hip_bf16.h>

// ---- problem constants ----
#define HIDDEN 2048
#define NH 16
#define NKV 8
#define HD 128
#define TN 512      // T_NOISE
#define TC 1536     // T_CTX
#define TNEW 2048   // TC + TN
#define MAXKV 8192

using u16 = unsigned short;
using u32 = unsigned int;

typedef short short8 __attribute__((ext_vector_type(8)));
typedef float floatx4 __attribute__((ext_vector_type(4)));

__device__ __forceinline__ u16 f2bf(float f) {
  u32 u = __float_as_uint(f);
  u += 0x7FFFu + ((u >> 16) & 1u);   // round-to-nearest-even
  return (u16)(u >> 16);
}

__device__ __forceinline__ uint4 pack8(const float* f) {
  uint4 r;
  r.x = (u32)f2bf(f[0]) | ((u32)f2bf(f[1]) << 16);
  r.y = (u32)f2bf(f[2]) | ((u32)f2bf(f[3]) << 16);
  r.z = (u32)f2bf(f[4]) | ((u32)f2bf(f[5]) << 16);
  r.w = (u32)f2bf(f[6]) | ((u32)f2bf(f[7]) << 16);
  return r;
}

__device__ __forceinline__ short8 ldfrag(const u16* p) {
  uint4 v = *(const uint4*)p;
  return __builtin_bit_cast(short8, v);
}

// async global->LDS, 16B per lane.
// l MUST be wave-uniform: HW writes lane i's 16B at l + i*16.
__device__ __forceinline__ void gload16(const void* g, void* l) {
  __builtin_amdgcn_global_load_lds(
      (const __attribute__((address_space(1))) u32*)g,
      (__attribute__((address_space(3))) u32*)l, 16, 0, 0);
}

// ============================================================================
// 1) Copy kv caches to output, skipping the scatter window. Also emits bf16
//    shadow caches for attention: Kb[head][s][h], VbT[head][h][s] (V transposed)
//    for rows < cache_len (new rows are shadowed by k_post/v_post).
// ============================================================================
__global__ __launch_bounds__(256) void cache_copy(
    const float4* __restrict__ inK, const float4* __restrict__ inV,
    float4* __restrict__ outK, float4* __restrict__ outV,
    const int* __restrict__ clp, u16* __restrict__ Kb, u16* __restrict__ VbT)
{
  const int cl = *clp;
  long long idx = (long long)blockIdx.x * 256 + threadIdx.x;
  const long long per = (long long)NH * MAXKV * (HD / 4);   // 4,194,304
  const float4* src; float4* dst; bool isv;
  long long r = idx;
  if (r < per) { src = inK; dst = outK; isv = false; }
  else { r -= per; src = inV; dst = outV; isv = true; }
  int row = (int)((r >> 5) & (MAXKV - 1));  // s index within a head
  if (row >= cl && row < cl + TNEW) return; // will be written by scatter
  float4 v = src[r];
  dst[r] = v;
  if (row < cl) {
    if (!isv) {
      if (Kb) {
        uint2 p;
        p.x = (u32)f2bf(v.x) | ((u32)f2bf(v.y) << 16);
        p.y = (u32)f2bf(v.z) | ((u32)f2bf(v.w) << 16);
        *(uint2*)(Kb + (size_t)r * 4) = p;
      }
    } else if (VbT) {
      int head = (int)(r >> 18);            // r / (MAXKV*32)
      int h0 = ((int)r & 31) * 4;
      size_t basev = ((size_t)head * HD + h0) * MAXKV + row;
      VbT[basev]             = f2bf(v.x);
      VbT[basev + MAXKV]     = f2bf(v.y);
      VbT[basev + 2 * MAXKV] = f2bf(v.z);
      VbT[basev + 3 * MAXKV] = f2bf(v.w);
    }
  }
}

// ============================================================================
// 2) GEMM, f32 in/out, bf16 MFMA 16x16x32. 64x64 tile, 4 waves (2x2).
// ============================================================================
__global__ __launch_bounds__(256) void gemm_bf16(
    const float* __restrict__ A0, int rows0, const float* __restrict__ A1,
    const float* __restrict__ B0, const float* __restrict__ B1, int Nhalf,
    float* __restrict__ C0, float* __restrict__ C1,
    int M, int N, int K, int ksteps)
{
  __shared__ u16 As[64 * 40];   // [row][k], stride 40
  __shared__ u16 Bs[64 * 40];   // [n][k] transposed, stride 40
  const int tid = threadIdx.x;
  const int lane = tid & 63;
  const int wave = tid >> 6;
  const int quad = lane >> 4;
  const int m16 = lane & 15;
  const int bm = blockIdx.y * 64;
  const int bn = blockIdx.x * 64;
  const int wm = (wave >> 1) * 32;
  const int wn = (wave & 1) * 32;
  const int z = blockIdx.z;
  const int kbase = z * ksteps * 32;

  const float* B = (bn < Nhalf) ? B0 : B1;
  float*       C = (bn < Nhalf) ? C0 : C1;
  const int n0 = (bn < Nhalf) ? bn : bn - Nhalf;
  const int strideN = (bn < Nhalf) ? Nhalf : (N - Nhalf);

  floatx4 acc[2][2];
#pragma unroll
  for (int i = 0; i < 2; i++)
#pragma unroll
    for (int j = 0; j < 2; j++)
#pragma unroll
      for (int r = 0; r < 4; r++) acc[i][j][r] = 0.0f;

  const int arow = tid >> 2, akg = (tid & 3) * 8;  // A stage: 64 rows x 32 k
  const int brow = tid >> 3, bng = (tid & 7) * 8;  // B stage: 32 k x 64 n
  const int garow = bm + arow;
  const float* Ap = (garow < rows0) ? (A0 + (size_t)garow * K)
                                    : (A1 + (size_t)(garow - rows0) * K);

  for (int ks = 0; ks < ksteps; ks++) {
    const int k0 = kbase + ks * 32;
    if (k0 >= K) break;
    float av[8];
    *(float4*)(av)     = *(const float4*)(Ap + k0 + akg);
    *(float4*)(av + 4) = *(const float4*)(Ap + k0 + akg + 4);
    *(uint4*)&As[arow * 40 + akg] = pack8(av);

    float bv[8];
    const float* Bp = B + (size_t)(k0 + brow) * strideN + n0 + bng;
    *(float4*)(bv)     = *(const float4*)(Bp);
    *(float4*)(bv + 4) = *(const float4*)(Bp + 4);
#pragma unroll
    for (int j = 0; j < 8; j++) Bs[(bng + j) * 40 + brow] = f2bf(bv[j]);

    __syncthreads();

    short8 a0 = ldfrag(&As[(wm + m16) * 40 + quad * 8]);
    short8 a1 = ldfrag(&As[(wm + 16 + m16) * 40 + quad * 8]);
    short8 b0 = ldfrag(&Bs[(wn + m16) * 40 + quad * 8]);
    short8 b1 = ldfrag(&Bs[(wn + 16 + m16) * 40 + quad * 8]);
    acc[0][0] = __builtin_amdgcn_mfma_f32_16x16x32_bf16(a0, b0, acc[0][0], 0, 0, 0);
    acc[0][1] = __builtin_amdgcn_mfma_f32_16x16x32_bf16(a0, b1, acc[0][1], 0, 0, 0);
    acc[1][0] = __builtin_amdgcn_mfma_f32_16x16x32_bf16(a1, b0, acc[1][0], 0, 0, 0);
    acc[1][1] = __builtin_amdgcn_mfma_f32_16x16x32_bf16(a1, b1, acc[1][1], 0, 0, 0);

    __syncthreads();
  }

  const size_t zoff = (size_t)z * M * Nhalf;
#pragma unroll
  for (int mt = 0; mt < 2; mt++)
#pragma unroll
    for (int nt = 0; nt < 2; nt++)
#pragma unroll
      for (int r = 0; r < 4; r++) {
        int row = bm + wm + mt * 16 + quad * 4 + r;  // C/D: row = quad*4 + reg
        int col = wn + nt * 16 + m16;                // within 64-tile
        C[zoff + (size_t)row * strideN + n0 + col] = acc[mt][nt][r];
      }
}

// ============================================================================
// 2b) reduce 4 split-K partials: C = sum_z P[z]
// ============================================================================
__global__ __launch_bounds__(256) void reduce4(
    const float4* __restrict__ P, float4* __restrict__ C, int n4)
{
  int idx = blockIdx.x * 256 + threadIdx.x;
  if (idx >= n4) return;
  float4 a = P[idx], b = P[idx + n4], c = P[idx + 2 * n4], d = P[idx + 3 * n4];
  float4 r;
  r.x = (a.x + b.x) + (c.x + d.x);
  r.y = (a.y + b.y) + (c.y + d.y);
  r.z = (a.z + b.z) + (c.z + d.z);
  r.w = (a.w + b.w) + (c.w + d.w);
  C[idx] = r;
}

// ============================================================================
// 3) Q post: RMSNorm(q_scale) + RoPE + fold sm_scale*log2e, emit bf16
// ============================================================================
__global__ __launch_bounds__(64) void q_post_k(
    const float* __restrict__ qproj, const int* __restrict__ npos,
    const float* __restrict__ qscale, u16* __restrict__ qbf)
{
  const int t = blockIdx.x, n = blockIdx.y, i = threadIdx.x;
  const size_t base = (size_t)t * HIDDEN + n * HD;
  const float x1 = qproj[base + i];
  const float x2 = qproj[base + i + 64];
  float ss = x1 * x1 + x2 * x2;
#pragma unroll
  for (int m = 1; m < 64; m <<= 1) ss += __shfl_xor(ss, m, 64);
  const float rstd = rsqrtf(ss * (1.0f / HD) + 1e-6f);
  float y1 = x1 * rstd * qscale[i];
  float y2 = x2 * rstd * qscale[i + 64];
  const float pos = (float)npos[t];
  const float ang = pos * exp2f(-(float)i * (19.931568569324174f / 64.0f));
  const float c = cosf(ang), s = sinf(ang);
  const float sc = 0.08838834764831845f * 1.4426950408889634f;  // sm_scale*log2e
  qbf[base + i]      = f2bf((y1 * c - y2 * s) * sc);
  qbf[base + i + 64] = f2bf((y2 * c + y1 * s) * sc);
}

// ============================================================================
// 4) K post: RMSNorm(k_scale) + RoPE, scatter f32 into out cache (GQA repeat)
//    + bf16 shadow Kb[head][s][h]
// ============================================================================
__global__ __launch_bounds__(64) void k_post_k(
    const float* __restrict__ kproj, const int* __restrict__ ctxpos,
    const int* __restrict__ npos, const float* __restrict__ kscale,
    const int* __restrict__ clp, float* __restrict__ outK, u16* __restrict__ Kb)
{
  const int t = blockIdx.x, kh = blockIdx.y, i = threadIdx.x;
  const int cl = *clp;
  const size_t base = (size_t)t * (NKV * HD) + kh * HD;
  const float x1 = kproj[base + i];
  const float x2 = kproj[base + i + 64];
  float ss = x1 * x1 + x2 * x2;
#pragma unroll
  for (int m = 1; m < 64; m <<= 1) ss += __shfl_xor(ss, m, 64);
  const float rstd = rsqrtf(ss * (1.0f / HD) + 1e-6f);
  float y1 = x1 * rstd * kscale[i];
  float y2 = x2 * rstd * kscale[i + 64];
  const int posi = (t < TC) ? ctxpos[t] : npos[t - TC];
  const float ang = (float)posi * exp2f(-(float)i * (19.931568569324174f / 64.0f));
  const float c = cosf(ang), s = sinf(ang);
  const float o1 = y1 * c - y2 * s;
  const float o2 = y2 * c + y1 * s;
  const size_t row = (size_t)cl + t;
  const size_t b0 = ((size_t)(2 * kh) * MAXKV + row) * HD;
  const size_t b1 = ((size_t)(2 * kh + 1) * MAXKV + row) * HD;
  outK[b0 + i] = o1; outK[b0 + i + 64] = o2;
  outK[b1 + i] = o1; outK[b1 + i + 64] = o2;
  if (Kb) {
    const u16 s1 = f2bf(o1), s2 = f2bf(o2);
    Kb[b0 + i] = s1; Kb[b0 + i + 64] = s2;
    Kb[b1 + i] = s1; Kb[b1 + i + 64] = s2;
  }
}

// ============================================================================
// 5) V post: scatter v_proj rows into out cache (GQA repeat)
//    + bf16 transposed shadow VbT[head][h][s]
// ============================================================================
__global__ __launch_bounds__(128) void v_post_k(
    const float* __restrict__ vproj, const int* __restrict__ clp,
    float* __restrict__ outV, u16* __restrict__ VbT)
{
  const int t = blockIdx.x, kh = blockIdx.y, h = threadIdx.x;
  const int cl = *clp;
  const float v = vproj[(size_t)t * (NKV * HD) + kh * HD + h];
  const size_t row = (size_t)cl + t;
  outV[((size_t)(2 * kh) * MAXKV + row) * HD + h] = v;
  outV[((size_t)(2 * kh + 1) * MAXKV + row) * HD + h] = v;
  if (VbT) {
    const u16 vb = f2bf(v);
    VbT[((size_t)(2 * kh) * HD + h) * MAXKV + row] = vb;
    VbT[((size_t)(2 * kh + 1) * HD + h) * MAXKV + row] = vb;
  }
}

// ============================================================================
// 6) Flash attention from bf16 shadow caches. 1D grid, XCD-bijective remap so
//    the 8 Q-tile blocks sharing a (head, split) KV chunk land on one XCD.
//    Staging is pure global_load_lds (K with T2 XOR-swizzled SOURCE address,
//    linear LDS dest; V from pre-transposed VbT). Double-buffered with counted
//    vmcnt (raw s_barrier, never drain to 0 mid-loop).
//    NOTE: global_load_lds LDS operand must be WAVE-UNIFORM; HW adds lane*16.
// ============================================================================
__global__ __launch_bounds__(256) void attn_sh(
    const u16* __restrict__ qbf, const u16* __restrict__ Kb,
    const u16* __restrict__ VbT, const int* __restrict__ clp,
    float* __restrict__ Opart, float* __restrict__ Oml, int splits)
{
  __shared__ u16 Ks[2][32 * 128];   // [s][h], rows XOR-swizzled by (row&7)<<4 bytes
  __shared__ u16 Vt[2][128 * 32];   // [h][s], stride 32
  __shared__ u16 Ps[4][16 * 40];    // per-wave P, [t][s], stride 40

  const int tid = threadIdx.x;
  const int lane = tid & 63, wave = tid >> 6;
  const int quad = lane >> 4, m16 = lane & 15;

  // XCD-bijective remap: blocks with same (head, z) share XCD c = pair/ppx
  const int lin = blockIdx.x;
  const int ppx = (NH * splits) >> 3;         // pairs per XCD
  const int c = lin & 7;
  const int jj = lin >> 3;
  const int pair = c * ppx + (jj % ppx);
  const int x = jj / ppx;
  const int head = pair & (NH - 1);
  const int z = pair >> 4;

  const int qbase = x * 64 + wave * 16;
  const int Svalid = *clp + TNEW;
  const int ntiles = (Svalid + 31) >> 5;
  const int per = (ntiles + splits - 1) / splits;
  const int it0 = z * per;
  const int it1 = (ntiles < it0 + per) ? ntiles : (it0 + per);

  short8 qf[4];
#pragma unroll
  for (int kb = 0; kb < 4; kb++)
    qf[kb] = ldfrag(&qbf[((size_t)(qbase + m16) * NH + head) * HD + kb * 32 + quad * 8]);

  floatx4 O[8];
#pragma unroll
  for (int i = 0; i < 8; i++)
#pragma unroll
    for (int r = 0; r < 4; r++) O[i][r] = 0.0f;
  float mrow[4], lrow[4];
#pragma unroll
  for (int r = 0; r < 4; r++) { mrow[r] = -1e30f; lrow[r] = 0.0f; }

  // staging geometry: thread t supplies the 16B that lands at LDS byte t*16
  // (wave-uniform LDS base wave*1024B; HW adds lane*16).
  const int krow = tid >> 4;                                 // K LDS row (half 0)
  const int ksrccol = ((tid & 15) * 16) ^ ((krow & 7) << 4); // pre-swizzled src col (bytes)
  const char* Kbase = (const char*)(Kb + (size_t)head * MAXKV * HD);
  const int vh = tid >> 2;                                   // V LDS row (half 0)
  const int vs8 = (tid & 3) * 8;
  const char* Vbase = (const char*)(VbT + (size_t)head * HD * MAXKV);
  u16* myPs = &Ps[wave][0];
  const int kxor = (m16 & 7) << 4;
  const int wb = wave * 512;                                 // wave LDS base, u16 units

  int b = 0;
  if (it0 < it1) {
    { // prologue: stage tile it0 into buffer 0
      const int s0 = it0 * 32;
      gload16(Kbase + ((size_t)(s0 + krow) << 8) + ksrccol,          &Ks[0][wb]);
      gload16(Kbase + ((size_t)(s0 + krow + 16) << 8) + ksrccol,     &Ks[0][2048 + wb]);
      gload16(Vbase + (((size_t)vh * MAXKV + s0 + vs8) << 1),        &Vt[0][wb]);
      gload16(Vbase + (((size_t)(vh + 64) * MAXKV + s0 + vs8) << 1), &Vt[0][2048 + wb]);
    }
    for (int it = it0; it < it1; ++it) {
      if (it + 1 < it1) {
        const int s1 = (it + 1) * 32;
        u16* KsN = &Ks[b ^ 1][0];
        u16* VtN = &Vt[b ^ 1][0];
        gload16(Kbase + ((size_t)(s1 + krow) << 8) + ksrccol,          KsN + wb);
        gload16(Kbase + ((size_t)(s1 + krow + 16) << 8) + ksrccol,     KsN + 2048 + wb);
        gload16(Vbase + (((size_t)vh * MAXKV + s1 + vs8) << 1),        VtN + wb);
        gload16(Vbase + (((size_t)(vh + 64) * MAXKV + s1 + vs8) << 1), VtN + 2048 + wb);
        // wait only the 4 oldest (current tile); keep the 4 prefetch in flight
        asm volatile("s_waitcnt vmcnt(4) lgkmcnt(0)" ::: "memory");
      } else {
        asm volatile("s_waitcnt vmcnt(0) lgkmcnt(0)" ::: "memory");
      }
      __builtin_amdgcn_s_barrier();
      __builtin_amdgcn_sched_barrier(0);

      const u16* KsB = &Ks[b][0];
      const u16* VtB = &Vt[b][0];
      const int s0 = it * 32;

      floatx4 sc[2];
#pragma unroll
      for (int st = 0; st < 2; st++) {
        floatx4 a;
#pragma unroll
        for (int r = 0; r < 4; r++) a[r] = 0.0f;
        const int rofs = (st * 16 + m16) * 128;
#pragma unroll
        for (int kb = 0; kb < 4; kb++) {
          short8 kf = ldfrag(&KsB[rofs + (((kb * 64 + quad * 16) ^ kxor) >> 1)]);
          a = __builtin_amdgcn_mfma_f32_16x16x32_bf16(qf[kb], kf, a, 0, 0, 0);
        }
        const int scol = s0 + st * 16 + m16;
        if (scol >= Svalid) {
#pragma unroll
          for (int r = 0; r < 4; r++) a[r] = -1e30f;
        }
        sc[st] = a;
      }

      float alpha[4];
#pragma unroll
      for (int r = 0; r < 4; r++) {
        float mx = fmaxf(sc[0][r], sc[1][r]);
        mx = fmaxf(mx, __shfl_xor(mx, 1, 64));
        mx = fmaxf(mx, __shfl_xor(mx, 2, 64));
        mx = fmaxf(mx, __shfl_xor(mx, 4, 64));
        mx = fmaxf(mx, __shfl_xor(mx, 8, 64));
        const float mn = fmaxf(mrow[r], mx);
        alpha[r] = exp2f(mrow[r] - mn);
        const float p0 = exp2f(sc[0][r] - mn);
        const float p1 = exp2f(sc[1][r] - mn);
        sc[0][r] = p0; sc[1][r] = p1;
        float rs = p0 + p1;
        rs += __shfl_xor(rs, 1, 64);
        rs += __shfl_xor(rs, 2, 64);
        rs += __shfl_xor(rs, 4, 64);
        rs += __shfl_xor(rs, 8, 64);
        lrow[r] = lrow[r] * alpha[r] + rs;
        mrow[r] = mn;
      }
#pragma unroll
      for (int hb = 0; hb < 8; hb++)
#pragma unroll
        for (int r = 0; r < 4; r++) O[hb][r] *= alpha[r];

#pragma unroll
      for (int st = 0; st < 2; st++)
#pragma unroll
        for (int r = 0; r < 4; r++)
          myPs[(quad * 4 + r) * 40 + st * 16 + m16] = f2bf(sc[st][r]);
      short8 pfr = ldfrag(&myPs[m16 * 40 + quad * 8]);
#pragma unroll
      for (int hb = 0; hb < 8; hb++) {
        short8 vf = ldfrag(&VtB[(hb * 16 + m16) * 32 + quad * 8]);
        O[hb] = __builtin_amdgcn_mfma_f32_16x16x32_bf16(pfr, vf, O[hb], 0, 0, 0);
      }

      asm volatile("s_waitcnt lgkmcnt(0)" ::: "memory");
      __builtin_amdgcn_s_barrier();
      __builtin_amdgcn_sched_barrier(0);
      b ^= 1;
    }
  }

  // write unnormalized partials + (m,l)
  const size_t zbase = (size_t)z * TN * NH;
  const int trow = qbase + quad * 4;
#pragma unroll
  for (int hb = 0; hb < 8; hb++)
#pragma unroll
    for (int r = 0; r < 4; r++)
      Opart[(zbase + (size_t)(trow + r) * NH + head) * HD + hb * 16 + m16] = O[hb][r];
  if (m16 == 0) {
#pragma unroll
    for (int r = 0; r < 4; r++) {
      Oml[(zbase + (size_t)(trow + r) * NH + head) * 2 + 0] = mrow[r];
      Oml[(zbase + (size_t)(trow + r) * NH + head) * 2 + 1] = lrow[r];
    }
  }
}

// ============================================================================
// 6-legacy) fallback attention reading f32 caches (used if ws too small)
// ============================================================================
__global__ __launch_bounds__(256) void attn_k(
    const u16* __restrict__ qbf, const float* __restrict__ outK,
    const float* __restrict__ outV, const int* __restrict__ clp,
    float* __restrict__ Opart, float* __restrict__ Oml)
{
  __shared__ u16 Ksl[32 * 136];
  __shared__ u16 Vtl[128 * 40];
  __shared__ u16 Psl[4 * 16 * 40];
  const int tid = threadIdx.x;
  const int lane = tid & 63, wave = tid >> 6;
  const int quad = lane >> 4, m16 = lane & 15;
  const int head = blockIdx.y;
  const int qbase = blockIdx.x * 64 + wave * 16;
  const int z = blockIdx.z, splits = gridDim.z;
  const int Svalid = *clp + TNEW;
  const int ntiles = (Svalid + 31) >> 5;
  const int per = (ntiles + splits - 1) / splits;
  const int it0 = z * per;
  const int it1 = min(ntiles, it0 + per);

  short8 qf[4];
#pragma unroll
  for (int kb = 0; kb < 4; kb++)
    qf[kb] = ldfrag(&qbf[((size_t)(qbase + m16) * NH + head) * HD + kb * 32 + quad * 8]);

  floatx4 O[8];
#pragma unroll
  for (int i = 0; i < 8; i++)
#pragma unroll
    for (int r = 0; r < 4; r++) O[i][r] = 0.0f;
  float mrow[4], lrow[4];
#pragma unroll
  for (int r = 0; r < 4; r++) { mrow[r] = -1e30f; lrow[r] = 0.0f; }

  const int sstage = tid >> 3;
  const int hg = (tid & 7) * 16;

  for (int it = it0; it < it1; it++) {
    const int s0 = it * 32;
    {
      int srow = s0 + sstage; if (srow > MAXKV - 1) srow = MAXKV - 1;
      const float* kp = outK + ((size_t)head * MAXKV + srow) * HD + hg;
      float tv[16];
      *(float4*)(tv)      = *(const float4*)(kp);
      *(float4*)(tv + 4)  = *(const float4*)(kp + 4);
      *(float4*)(tv + 8)  = *(const float4*)(kp + 8);
      *(float4*)(tv + 12) = *(const float4*)(kp + 12);
      *(uint4*)&Ksl[sstage * 136 + hg]     = pack8(tv);
      *(uint4*)&Ksl[sstage * 136 + hg + 8] = pack8(tv + 8);
      const float* vp = outV + ((size_t)head * MAXKV + srow) * HD + hg;
      float vv[16];
      *(float4*)(vv)      = *(const float4*)(vp);
      *(float4*)(vv + 4)  = *(const float4*)(vp + 4);
      *(float4*)(vv + 8)  = *(const float4*)(vp + 8);
      *(float4*)(vv + 12) = *(const float4*)(vp + 12);
#pragma unroll
      for (int j = 0; j < 16; j++) Vtl[(hg + j) * 40 + sstage] = f2bf(vv[j]);
    }
    __syncthreads();

    floatx4 sc[2];
#pragma unroll
    for (int st = 0; st < 2; st++) {
      floatx4 a;
#pragma unroll
      for (int r = 0; r < 4; r++) a[r] = 0.0f;
#pragma unroll
      for (int kb = 0; kb < 4; kb++) {
        short8 kf = ldfrag(&Ksl[(st * 16 + m16) * 136 + kb * 32 + quad * 8]);
        a = __builtin_amdgcn_mfma_f32_16x16x32_bf16(qf[kb], kf, a, 0, 0, 0);
      }
      const int scol = s0 + st * 16 + m16;
      if (scol >= Svalid) {
#pragma unroll
        for (int r = 0; r < 4; r++) a[r] = -1e30f;
      }
      sc[st] = a;
    }

    float alpha[4];
#pragma unroll
    for (int r = 0; r < 4; r++) {
      float mx = fmaxf(sc[0][r], sc[1][r]);
      mx = fmaxf(mx, __shfl_xor(mx, 1, 64));
      mx = fmaxf(mx, __shfl_xor(mx, 2, 64));
      mx = fmaxf(mx, __shfl_xor(mx, 4, 64));
      mx = fmaxf(mx, __shfl_xor(mx, 8, 64));
      const float mn = fmaxf(mrow[r], mx);
      alpha[r] = exp2f(mrow[r] - mn);
      const float p0 = exp2f(sc[0][r] - mn);
      const float p1 = exp2f(sc[1][r] - mn);
      sc[0][r] = p0; sc[1][r] = p1;
      float rs = p0 + p1;
      rs += __shfl_xor(rs, 1, 64);
      rs += __shfl_xor(rs, 2, 64);
      rs += __shfl_xor(rs, 4, 64);
      rs += __shfl_xor(rs, 8, 64);
      lrow[r] = lrow[r] * alpha[r] + rs;
      mrow[r] = mn;
    }
#pragma unroll
    for (int hb = 0; hb < 8; hb++)
#pragma unroll
      for (int r = 0; r < 4; r++) O[hb][r] *= alpha[r];

    u16* myPs = &Psl[wave * 640];
#pragma unroll
    for (int st = 0; st < 2; st++)
#pragma unroll
      for (int r = 0; r < 4; r++)
        myPs[(quad * 4 + r) * 40 + st * 16 + m16] = f2bf(sc[st][r]);
    short8 pf = ldfrag(&myPs[m16 * 40 + quad * 8]);
#pragma unroll
    for (int hb = 0; hb < 8; hb++) {
      short8 vf = ldfrag(&Vtl[(hb * 16 + m16) * 40 + quad * 8]);
      O[hb] = __builtin_amdgcn_mfma_f32_16x16x32_bf16(pf, vf, O[hb], 0, 0, 0);
    }
    __syncthreads();
  }

  const size_t zbase = (size_t)z * TN * NH;
  const int trow = qbase + quad * 4;
#pragma unroll
  for (int hb = 0; hb < 8; hb++)
#pragma unroll
    for (int r = 0; r < 4; r++)
      Opart[(zbase + (size_t)(trow + r) * NH + head) * HD + hb * 16 + m16] = O[hb][r];
  if (m16 == 0) {
#pragma unroll
    for (int r = 0; r < 4; r++) {
      Oml[(zbase + (size_t)(trow + r) * NH + head) * 2 + 0] = mrow[r];
      Oml[(zbase + (size_t)(trow + r) * NH + head) * 2 + 1] = lrow[r];
    }
  }
}

// ============================================================================
// 6b) combine split-S partials -> attnb [t][head][hd]
// ============================================================================
__global__ __launch_bounds__(128) void attn_combine(
    const float* __restrict__ Opart, const float* __restrict__ Oml,
    float* __restrict__ attnb, int splits)
{
  const int pair = blockIdx.x;   // t*NH + head
  const int h = threadIdx.x;
  float M = -1e30f;
  for (int zz = 0; zz < splits; zz++)
    M = fmaxf(M, Oml[((size_t)zz * TN * NH + pair) * 2]);
  float l = 0.0f, o = 0.0f;
  for (int zz = 0; zz < splits; zz++) {
    const float mi = Oml[((size_t)zz * TN * NH + pair) * 2];
    const float li = Oml[((size_t)zz * TN * NH + pair) * 2 + 1];
    const float w = exp2f(mi - M);
    l += li * w;
    o += Opart[((size_t)zz * TN * NH + pair) * HD + h] * w;
  }
  attnb[(size_t)pair * HD + h] = o / l;
}

// ============================================================================
// launch
// ============================================================================
extern "C" void kernel_launch(void* const* d_in, const int* in_sizes, int n_in,
                              void* d_out, int out_size, void* d_ws, size_t ws_size,
                              hipStream_t stream) {
  const float* x_noise       = (const float*)d_in[0];
  const float* target_hidden = (const float*)d_in[1];
  const int*   noise_pos     = (const int*)d_in[2];
  const int*   ctx_pos       = (const int*)d_in[3];
  const float* inK           = (const float*)d_in[4];
  const float* inV           = (const float*)d_in[5];
  const int*   cache_len     = (const int*)d_in[6];
  const float* wq            = (const float*)d_in[7];
  const float* wk            = (const float*)d_in[8];
  const float* wv            = (const float*)d_in[9];
  const float* wo            = (const float*)d_in[10];
  const float* q_scale       = (const float*)d_in[11];
  const float* k_scale       = (const float*)d_in[12];

  float* out0 = (float*)d_out;
  float* outK = out0 + (size_t)TN * HIDDEN;
  float* outV = outK + (size_t)NH * MAXKV * HD;

  // ---- workspace layout ----
  size_t off = 0;
  auto walloc = [&](size_t bytes) -> void* {
    void* p = (char*)d_ws + off;
    off += (bytes + 255) & ~(size_t)255;
    return p;
  };
  u16*   qbf   = (u16*)walloc((size_t)TN * HIDDEN * 2);
  float* attnb = (float*)walloc((size_t)TN * HIDDEN * 4);
  float* qproj = (float*)walloc((size_t)TN * HIDDEN * 4);
  float* kproj = (float*)walloc((size_t)TNEW * NKV * HD * 4);
  float* vproj = (float*)walloc((size_t)TNEW * NKV * HD * 4);

  const size_t PER_SPLIT = (size_t)TN * NH * HD * 4 + (size_t)TN * NH * 8;
  const size_t SHB = (size_t)NH * MAXKV * HD * sizeof(u16);   // 32 MB each
  const size_t GPART = (size_t)4 * TN * HIDDEN * 4;           // 16 MB
  auto maxsz = [](size_t a, size_t b) { return a > b ? a : b; };

  size_t avail = (ws_size > off) ? ws_size - off : 0;
  u16 *Kb = nullptr, *VbT = nullptr;
  int asplits = 0;
  if (avail >= 2 * SHB + maxsz(8 * PER_SPLIT, GPART))       asplits = 8;
  else if (avail >= 2 * SHB + maxsz(4 * PER_SPLIT, GPART))  asplits = 4;
  const bool shadow = (asplits > 0);
  if (shadow) {
    Kb  = (u16*)walloc(SHB);
    VbT = (u16*)walloc(SHB);
  }

  float* scratch = (float*)((char*)d_ws + off);
  const size_t avail2 = (ws_size > off) ? ws_size - off : 0;
  if (!shadow) {
    asplits = 2;
    if (avail2 >= 8 * PER_SPLIT) asplits = 8;
    else if (avail2 >= 4 * PER_SPLIT) asplits = 4;
  }
  float* Opart = scratch;
  float* Oml   = Opart + (size_t)asplits * TN * NH * HD;
  const bool ksplit = (avail2 >= GPART);
  float* gpart = scratch;   // shared with Opart (phases don't overlap)

  cache_copy<<<dim3(32768), dim3(256), 0, stream>>>(
      (const float4*)inK, (const float4*)inV, (float4*)outK, (float4*)outV,
      cache_len, Kb, VbT);

  // Q projection: split-K x4
  if (ksplit) {
    gemm_bf16<<<dim3(HIDDEN / 64, TN / 64, 4), dim3(256), 0, stream>>>(
        x_noise, TN, x_noise, wq, wq, HIDDEN, gpart, gpart, TN, HIDDEN, HIDDEN, 16);
    reduce4<<<dim3((TN * HIDDEN / 4 + 255) / 256), dim3(256), 0, stream>>>(
        (const float4*)gpart, (float4*)qproj, TN * HIDDEN / 4);
  } else {
    gemm_bf16<<<dim3(HIDDEN / 64, TN / 64, 1), dim3(256), 0, stream>>>(
        x_noise, TN, x_noise, wq, wq, HIDDEN, qproj, qproj, TN, HIDDEN, HIDDEN, 64);
  }

  // merged K+V projection (N = 2048 -> 32x32 grid)
  gemm_bf16<<<dim3(2 * NKV * HD / 64, TNEW / 64, 1), dim3(256), 0, stream>>>(
      target_hidden, TC, x_noise, wk, wv, NKV * HD, kproj, vproj,
      TNEW, 2 * NKV * HD, HIDDEN, 64);

  q_post_k<<<dim3(TN, NH), dim3(64), 0, stream>>>(qproj, noise_pos, q_scale, qbf);
  k_post_k<<<dim3(TNEW, NKV), dim3(64), 0, stream>>>(
      kproj, ctx_pos, noise_pos, k_scale, cache_len, outK, Kb);
  v_post_k<<<dim3(TNEW, NKV), dim3(128), 0, stream>>>(vproj, cache_len, outV, VbT);

  if (shadow) {
    attn_sh<<<dim3((TN / 64) * NH * asplits), dim3(256), 0, stream>>>(
        qbf, Kb, VbT, cache_len, Opart, Oml, asplits);
  } else {
    attn_k<<<dim3(TN / 64, NH, asplits), dim3(256), 0, stream>>>(
        qbf, outK, outV, cache_len, Opart, Oml);
  }
  attn_combine<<<dim3(TN * NH), dim3(128), 0, stream>>>(Opart, Oml, attnb, asplits);

  // output projection: split-K x4
  if (ksplit) {
    gemm_bf16<<<dim3(HIDDEN / 64, TN / 64, 4), dim3(256), 0, stream>>>(
        attnb, TN, attnb, wo, wo, HIDDEN, gpart, gpart, TN, HIDDEN, HIDDEN, 16);
    reduce4<<<dim3((TN * HIDDEN / 4 + 255) / 256), dim3(256), 0, stream>>>(
        (const float4*)gpart, (float4*)out0, TN * HIDDEN / 4);
  } else {
    gemm_bf16<<<dim3(HIDDEN / 64, TN / 64, 1), dim3(256), 0, stream>>>(
        attnb, TN, attnb, wo, wo, HIDDEN, out0, out0, TN, HIDDEN, HIDDEN, 64);
  }
}

// Round 3
// 528.853 us; speedup vs baseline: 1.0694x; 1.0694x over previous
//
#include <hip/hip_runtime.h>
#include <hip/hip_bf16.h>

// ---- problem constants ----
#define HIDDEN 2048
#define NH 16
#define NKV 8
#define HD 128
#define TN 512      // T_NOISE
#define TC 1536     // T_CTX
#define TNEW 2048   // TC + TN
#define MAXKV 8192

using u16 = unsigned short;
using u32 = unsigned int;

typedef short short8 __attribute__((ext_vector_type(8)));
typedef float floatx4 __attribute__((ext_vector_type(4)));

__device__ __forceinline__ u16 f2bf(float f) {
  u32 u = __float_as_uint(f);
  u += 0x7FFFu + ((u >> 16) & 1u);   // round-to-nearest-even
  return (u16)(u >> 16);
}

__device__ __forceinline__ uint4 pack8(const float* f) {
  uint4 r;
  r.x = (u32)f2bf(f[0]) | ((u32)f2bf(f[1]) << 16);
  r.y = (u32)f2bf(f[2]) | ((u32)f2bf(f[3]) << 16);
  r.z = (u32)f2bf(f[4]) | ((u32)f2bf(f[5]) << 16);
  r.w = (u32)f2bf(f[6]) | ((u32)f2bf(f[7]) << 16);
  return r;
}

__device__ __forceinline__ short8 ldfrag(const u16* p) {
  uint4 v = *(const uint4*)p;
  return __builtin_bit_cast(short8, v);
}

// async global->LDS, 16B per lane.
// l MUST be wave-uniform: HW writes lane i's 16B at l + i*16.
__device__ __forceinline__ void gload16(const void* g, void* l) {
  __builtin_amdgcn_global_load_lds(
      (const __attribute__((address_space(1))) u32*)g,
      (__attribute__((address_space(3))) u32*)l, 16, 0, 0);
}

// ============================================================================
// 0a) f32 -> bf16 convert (vectorized)
// ============================================================================
__global__ __launch_bounds__(256) void conv_bf16(
    const float4* __restrict__ in, uint2* __restrict__ out, int n4)
{
  int idx = blockIdx.x * 256 + threadIdx.x;
  if (idx >= n4) return;
  float4 v = in[idx];
  uint2 r;
  r.x = (u32)f2bf(v.x) | ((u32)f2bf(v.y) << 16);
  r.y = (u32)f2bf(v.z) | ((u32)f2bf(v.w) << 16);
  out[idx] = r;
}

// ============================================================================
// 0b) f32 [K][N] -> bf16 [N][K] transpose (LDS-tiled 64x64)
// ============================================================================
__global__ __launch_bounds__(256) void transpose_bf16(
    const float* __restrict__ w, u16* __restrict__ wT, int K, int N)
{
  __shared__ float t[64][65];
  const int bk = blockIdx.y * 64, bn = blockIdx.x * 64;
  const int tid = threadIdx.x;
  const int r = tid >> 4, c4 = (tid & 15) * 4;
#pragma unroll
  for (int rr = 0; rr < 4; rr++) {
    float4 v = *(const float4*)(w + (size_t)(bk + rr * 16 + r) * N + bn + c4);
    t[rr * 16 + r][c4 + 0] = v.x;
    t[rr * 16 + r][c4 + 1] = v.y;
    t[rr * 16 + r][c4 + 2] = v.z;
    t[rr * 16 + r][c4 + 3] = v.w;
  }
  __syncthreads();
  const int n = tid >> 2, k16 = (tid & 3) * 16;
  u32 wbuf[8];
#pragma unroll
  for (int jj = 0; jj < 8; jj++) {
    float lo = t[k16 + 2 * jj][n], hi = t[k16 + 2 * jj + 1][n];
    wbuf[jj] = (u32)f2bf(lo) | ((u32)f2bf(hi) << 16);
  }
  *(uint4*)(&wT[(size_t)(bn + n) * K + bk + k16])     = *(uint4*)(wbuf);
  *(uint4*)(&wT[(size_t)(bn + n) * K + bk + k16 + 8]) = *(uint4*)(wbuf + 4);
}

// ============================================================================
// 1) Copy kv caches to output, skipping the scatter window. Also emits bf16
//    shadow caches for attention: Kb[head][s][h], VbT[head][h][s].
// ============================================================================
__global__ __launch_bounds__(256) void cache_copy(
    const float4* __restrict__ inK, const float4* __restrict__ inV,
    float4* __restrict__ outK, float4* __restrict__ outV,
    const int* __restrict__ clp, u16* __restrict__ Kb, u16* __restrict__ VbT)
{
  const int cl = *clp;
  long long idx = (long long)blockIdx.x * 256 + threadIdx.x;
  const long long per = (long long)NH * MAXKV * (HD / 4);   // 4,194,304
  const float4* src; float4* dst; bool isv;
  long long r = idx;
  if (r < per) { src = inK; dst = outK; isv = false; }
  else { r -= per; src = inV; dst = outV; isv = true; }
  int row = (int)((r >> 5) & (MAXKV - 1));  // s index within a head
  if (row >= cl && row < cl + TNEW) return; // will be written by scatter
  float4 v = src[r];
  dst[r] = v;
  if (row < cl) {
    if (!isv) {
      if (Kb) {
        uint2 p;
        p.x = (u32)f2bf(v.x) | ((u32)f2bf(v.y) << 16);
        p.y = (u32)f2bf(v.z) | ((u32)f2bf(v.w) << 16);
        *(uint2*)(Kb + (size_t)r * 4) = p;
      }
    } else if (VbT) {
      int head = (int)(r >> 18);            // r / (MAXKV*32)
      int h0 = ((int)r & 31) * 4;
      size_t basev = ((size_t)head * HD + h0) * MAXKV + row;
      VbT[basev]             = f2bf(v.x);
      VbT[basev + MAXKV]     = f2bf(v.y);
      VbT[basev + 2 * MAXKV] = f2bf(v.z);
      VbT[basev + 3 * MAXKV] = f2bf(v.w);
    }
  }
}

// ============================================================================
// 2) NEW GEMM: bf16 A [M][K], bf16 B^T [N][K], f32 C. 128x128 tile, BK=32,
//    4 waves (2x2, each 64x64 = 4x4 MFMA frags). global_load_lds staging,
//    double-buffered, counted vmcnt. XCD sub-grid swizzle.
//    A rows: A0 (first rows0) then A1. B/C cols: [0,Nhalf)->B0/C0 else B1/C1.
//    Split-K via blockIdx.z (ksteps each), C offset z*M*Nhalf.
// ============================================================================
__global__ __launch_bounds__(256) void gemm_v2(
    const u16* __restrict__ A0, int rows0, const u16* __restrict__ A1,
    const u16* __restrict__ B0, const u16* __restrict__ B1, int Nhalf,
    float* __restrict__ C0, float* __restrict__ C1,
    int M, int N, int K, int ksteps)
{
  __shared__ u16 As[2][128 * 32];
  __shared__ u16 Bs[2][128 * 32];
  const int tid = threadIdx.x;
  const int lane = tid & 63, wave = tid >> 6;
  const int quad = lane >> 4, m16 = lane & 15;

  // XCD sub-grid swizzle: each XCD owns a (gx/4)x(gy/2) rectangle of tiles
  const int gx = gridDim.x, gy = gridDim.y;
  int bx = blockIdx.x, by = blockIdx.y;
  if (((gx & 3) == 0) && ((gy & 1) == 0)) {
    const int lin = bx + gx * by;
    const int c = lin & 7, j = lin >> 3;
    const int sw = gx >> 2, sh = gy >> 1;
    bx = (c & 3) * sw + j % sw;
    by = (c >> 2) * sh + j / sw;
  }
  const int bm = by * 128, bn = bx * 128;
  const int wm = (wave >> 1) * 64, wn = (wave & 1) * 64;
  const int z = blockIdx.z;
  const int kbase = z * ksteps * 32;

  const u16* B = (bn < Nhalf) ? B0 : B1;
  float*     C = (bn < Nhalf) ? C0 : C1;
  const int n0 = (bn < Nhalf) ? bn : bn - Nhalf;
  const int strideN = (bn < Nhalf) ? Nhalf : (N - Nhalf);

  floatx4 acc[4][4];
#pragma unroll
  for (int i = 0; i < 4; i++)
#pragma unroll
    for (int j = 0; j < 4; j++)
#pragma unroll
      for (int r = 0; r < 4; r++) acc[i][j][r] = 0.0f;

  // staging: thread t supplies 16B landing at LDS byte t*16 of each half-tile
  const int srow = tid >> 2;          // 0..63 (row within half)
  const int sk = (tid & 3) * 8;       // u16 k-offset
  const int ar0 = bm + srow, ar1 = bm + srow + 64;
  const u16* Arow0 = (ar0 < rows0) ? (A0 + (size_t)ar0 * K)
                                   : (A1 + (size_t)(ar0 - rows0) * K);
  const u16* Arow1 = (ar1 < rows0) ? (A0 + (size_t)ar1 * K)
                                   : (A1 + (size_t)(ar1 - rows0) * K);
  const u16* Brow0 = B + (size_t)(n0 + srow) * K;
  const u16* Brow1 = B + (size_t)(n0 + srow + 64) * K;
  const int wb = wave * 512;          // wave-uniform LDS base (u16 units)

  // prologue: stage first K-step into buffer 0
  {
    const int k0 = kbase;
    gload16(Arow0 + k0 + sk, &As[0][wb]);
    gload16(Arow1 + k0 + sk, &As[0][2048 + wb]);
    gload16(Brow0 + k0 + sk, &Bs[0][wb]);
    gload16(Brow1 + k0 + sk, &Bs[0][2048 + wb]);
  }
  int b = 0;
  for (int ks = 0; ks < ksteps; ks++) {
    if (ks + 1 < ksteps) {
      const int k1 = kbase + (ks + 1) * 32;
      gload16(Arow0 + k1 + sk, &As[b ^ 1][wb]);
      gload16(Arow1 + k1 + sk, &As[b ^ 1][2048 + wb]);
      gload16(Brow0 + k1 + sk, &Bs[b ^ 1][wb]);
      gload16(Brow1 + k1 + sk, &Bs[b ^ 1][2048 + wb]);
      asm volatile("s_waitcnt vmcnt(4)" ::: "memory");  // current tile only
    } else {
      asm volatile("s_waitcnt vmcnt(0)" ::: "memory");
    }
    __builtin_amdgcn_s_barrier();
    __builtin_amdgcn_sched_barrier(0);

    short8 af[4], bfr[4];
#pragma unroll
    for (int i = 0; i < 4; i++) {
      af[i]  = ldfrag(&As[b][(wm + i * 16 + m16) * 32 + quad * 8]);
      bfr[i] = ldfrag(&Bs[b][(wn + i * 16 + m16) * 32 + quad * 8]);
    }
#pragma unroll
    for (int i = 0; i < 4; i++)
#pragma unroll
      for (int j = 0; j < 4; j++)
        acc[i][j] = __builtin_amdgcn_mfma_f32_16x16x32_bf16(af[i], bfr[j], acc[i][j], 0, 0, 0);

    asm volatile("s_waitcnt lgkmcnt(0)" ::: "memory");
    __builtin_amdgcn_s_barrier();
    __builtin_amdgcn_sched_barrier(0);
    b ^= 1;
  }

  const size_t zoff = (size_t)z * M * Nhalf;
#pragma unroll
  for (int i = 0; i < 4; i++)
#pragma unroll
    for (int j = 0; j < 4; j++)
#pragma unroll
      for (int r = 0; r < 4; r++) {
        int row = bm + wm + i * 16 + quad * 4 + r;
        int col = wn + j * 16 + m16;
        C[zoff + (size_t)row * strideN + n0 + col] = acc[i][j][r];
      }
}

// ============================================================================
// 2-legacy) f32-input GEMM (fallback when workspace too small for converts)
// ============================================================================
__global__ __launch_bounds__(256) void gemm_bf16(
    const float* __restrict__ A0, int rows0, const float* __restrict__ A1,
    const float* __restrict__ B0, const float* __restrict__ B1, int Nhalf,
    float* __restrict__ C0, float* __restrict__ C1,
    int M, int N, int K, int ksteps)
{
  __shared__ u16 As[64 * 40];   // [row][k], stride 40
  __shared__ u16 Bs[64 * 40];   // [n][k] transposed, stride 40
  const int tid = threadIdx.x;
  const int lane = tid & 63;
  const int wave = tid >> 6;
  const int quad = lane >> 4;
  const int m16 = lane & 15;
  const int bm = blockIdx.y * 64;
  const int bn = blockIdx.x * 64;
  const int wm = (wave >> 1) * 32;
  const int wn = (wave & 1) * 32;
  const int z = blockIdx.z;
  const int kbase = z * ksteps * 32;

  const float* B = (bn < Nhalf) ? B0 : B1;
  float*       C = (bn < Nhalf) ? C0 : C1;
  const int n0 = (bn < Nhalf) ? bn : bn - Nhalf;
  const int strideN = (bn < Nhalf) ? Nhalf : (N - Nhalf);

  floatx4 acc[2][2];
#pragma unroll
  for (int i = 0; i < 2; i++)
#pragma unroll
    for (int j = 0; j < 2; j++)
#pragma unroll
      for (int r = 0; r < 4; r++) acc[i][j][r] = 0.0f;

  const int arow = tid >> 2, akg = (tid & 3) * 8;
  const int brow = tid >> 3, bng = (tid & 7) * 8;
  const int garow = bm + arow;
  const float* Ap = (garow < rows0) ? (A0 + (size_t)garow * K)
                                    : (A1 + (size_t)(garow - rows0) * K);

  for (int ks = 0; ks < ksteps; ks++) {
    const int k0 = kbase + ks * 32;
    if (k0 >= K) break;
    float av[8];
    *(float4*)(av)     = *(const float4*)(Ap + k0 + akg);
    *(float4*)(av + 4) = *(const float4*)(Ap + k0 + akg + 4);
    *(uint4*)&As[arow * 40 + akg] = pack8(av);

    float bv[8];
    const float* Bp = B + (size_t)(k0 + brow) * strideN + n0 + bng;
    *(float4*)(bv)     = *(const float4*)(Bp);
    *(float4*)(bv + 4) = *(const float4*)(Bp + 4);
#pragma unroll
    for (int j = 0; j < 8; j++) Bs[(bng + j) * 40 + brow] = f2bf(bv[j]);

    __syncthreads();

    short8 a0 = ldfrag(&As[(wm + m16) * 40 + quad * 8]);
    short8 a1 = ldfrag(&As[(wm + 16 + m16) * 40 + quad * 8]);
    short8 b0 = ldfrag(&Bs[(wn + m16) * 40 + quad * 8]);
    short8 b1 = ldfrag(&Bs[(wn + 16 + m16) * 40 + quad * 8]);
    acc[0][0] = __builtin_amdgcn_mfma_f32_16x16x32_bf16(a0, b0, acc[0][0], 0, 0, 0);
    acc[0][1] = __builtin_amdgcn_mfma_f32_16x16x32_bf16(a0, b1, acc[0][1], 0, 0, 0);
    acc[1][0] = __builtin_amdgcn_mfma_f32_16x16x32_bf16(a1, b0, acc[1][0], 0, 0, 0);
    acc[1][1] = __builtin_amdgcn_mfma_f32_16x16x32_bf16(a1, b1, acc[1][1], 0, 0, 0);

    __syncthreads();
  }

  const size_t zoff = (size_t)z * M * Nhalf;
#pragma unroll
  for (int mt = 0; mt < 2; mt++)
#pragma unroll
    for (int nt = 0; nt < 2; nt++)
#pragma unroll
      for (int r = 0; r < 4; r++) {
        int row = bm + wm + mt * 16 + quad * 4 + r;
        int col = wn + nt * 16 + m16;
        C[zoff + (size_t)row * strideN + n0 + col] = acc[mt][nt][r];
      }
}

// ============================================================================
// 2b) reduce 4 split-K partials: C = sum_z P[z]
// ============================================================================
__global__ __launch_bounds__(256) void reduce4(
    const float4* __restrict__ P, float4* __restrict__ C, int n4)
{
  int idx = blockIdx.x * 256 + threadIdx.x;
  if (idx >= n4) return;
  float4 a = P[idx], b = P[idx + n4], c = P[idx + 2 * n4], d = P[idx + 3 * n4];
  float4 r;
  r.x = (a.x + b.x) + (c.x + d.x);
  r.y = (a.y + b.y) + (c.y + d.y);
  r.z = (a.z + b.z) + (c.z + d.z);
  r.w = (a.w + b.w) + (c.w + d.w);
  C[idx] = r;
}

// ============================================================================
// 3) Q post: RMSNorm(q_scale) + RoPE + fold sm_scale*log2e, emit bf16
// ============================================================================
__global__ __launch_bounds__(64) void q_post_k(
    const float* __restrict__ qproj, const int* __restrict__ npos,
    const float* __restrict__ qscale, u16* __restrict__ qbf)
{
  const int t = blockIdx.x, n = blockIdx.y, i = threadIdx.x;
  const size_t base = (size_t)t * HIDDEN + n * HD;
  const float x1 = qproj[base + i];
  const float x2 = qproj[base + i + 64];
  float ss = x1 * x1 + x2 * x2;
#pragma unroll
  for (int m = 1; m < 64; m <<= 1) ss += __shfl_xor(ss, m, 64);
  const float rstd = rsqrtf(ss * (1.0f / HD) + 1e-6f);
  float y1 = x1 * rstd * qscale[i];
  float y2 = x2 * rstd * qscale[i + 64];
  const float pos = (float)npos[t];
  const float ang = pos * exp2f(-(float)i * (19.931568569324174f / 64.0f));
  const float c = cosf(ang), s = sinf(ang);
  const float sc = 0.08838834764831845f * 1.4426950408889634f;  // sm_scale*log2e
  qbf[base + i]      = f2bf((y1 * c - y2 * s) * sc);
  qbf[base + i + 64] = f2bf((y2 * c + y1 * s) * sc);
}

// ============================================================================
// 4) K post: RMSNorm(k_scale) + RoPE, scatter f32 into out cache (GQA repeat)
//    + bf16 shadow Kb[head][s][h]
// ============================================================================
__global__ __launch_bounds__(64) void k_post_k(
    const float* __restrict__ kproj, const int* __restrict__ ctxpos,
    const int* __restrict__ npos, const float* __restrict__ kscale,
    const int* __restrict__ clp, float* __restrict__ outK, u16* __restrict__ Kb)
{
  const int t = blockIdx.x, kh = blockIdx.y, i = threadIdx.x;
  const int cl = *clp;
  const size_t base = (size_t)t * (NKV * HD) + kh * HD;
  const float x1 = kproj[base + i];
  const float x2 = kproj[base + i + 64];
  float ss = x1 * x1 + x2 * x2;
#pragma unroll
  for (int m = 1; m < 64; m <<= 1) ss += __shfl_xor(ss, m, 64);
  const float rstd = rsqrtf(ss * (1.0f / HD) + 1e-6f);
  float y1 = x1 * rstd * kscale[i];
  float y2 = x2 * rstd * kscale[i + 64];
  const int posi = (t < TC) ? ctxpos[t] : npos[t - TC];
  const float ang = (float)posi * exp2f(-(float)i * (19.931568569324174f / 64.0f));
  const float c = cosf(ang), s = sinf(ang);
  const float o1 = y1 * c - y2 * s;
  const float o2 = y2 * c + y1 * s;
  const size_t row = (size_t)cl + t;
  const size_t b0 = ((size_t)(2 * kh) * MAXKV + row) * HD;
  const size_t b1 = ((size_t)(2 * kh + 1) * MAXKV + row) * HD;
  outK[b0 + i] = o1; outK[b0 + i + 64] = o2;
  outK[b1 + i] = o1; outK[b1 + i + 64] = o2;
  if (Kb) {
    const u16 s1 = f2bf(o1), s2 = f2bf(o2);
    Kb[b0 + i] = s1; Kb[b0 + i + 64] = s2;
    Kb[b1 + i] = s1; Kb[b1 + i + 64] = s2;
  }
}

// ============================================================================
// 5) V post: scatter v_proj rows into out cache (GQA repeat)
//    + bf16 transposed shadow VbT[head][h][s]
// ============================================================================
__global__ __launch_bounds__(128) void v_post_k(
    const float* __restrict__ vproj, const int* __restrict__ clp,
    float* __restrict__ outV, u16* __restrict__ VbT)
{
  const int t = blockIdx.x, kh = blockIdx.y, h = threadIdx.x;
  const int cl = *clp;
  const float v = vproj[(size_t)t * (NKV * HD) + kh * HD + h];
  const size_t row = (size_t)cl + t;
  outV[((size_t)(2 * kh) * MAXKV + row) * HD + h] = v;
  outV[((size_t)(2 * kh + 1) * MAXKV + row) * HD + h] = v;
  if (VbT) {
    const u16 vb = f2bf(v);
    VbT[((size_t)(2 * kh) * HD + h) * MAXKV + row] = vb;
    VbT[((size_t)(2 * kh + 1) * HD + h) * MAXKV + row] = vb;
  }
}

// ============================================================================
// 6) Flash attention from bf16 shadow caches (unchanged from round 2 — passed).
// ============================================================================
__global__ __launch_bounds__(256) void attn_sh(
    const u16* __restrict__ qbf, const u16* __restrict__ Kb,
    const u16* __restrict__ VbT, const int* __restrict__ clp,
    float* __restrict__ Opart, float* __restrict__ Oml, int splits)
{
  __shared__ u16 Ks[2][32 * 128];   // [s][h], rows XOR-swizzled by (row&7)<<4 bytes
  __shared__ u16 Vt[2][128 * 32];   // [h][s], stride 32
  __shared__ u16 Ps[4][16 * 40];    // per-wave P, [t][s], stride 40

  const int tid = threadIdx.x;
  const int lane = tid & 63, wave = tid >> 6;
  const int quad = lane >> 4, m16 = lane & 15;

  const int lin = blockIdx.x;
  const int ppx = (NH * splits) >> 3;         // pairs per XCD
  const int c = lin & 7;
  const int jj = lin >> 3;
  const int pair = c * ppx + (jj % ppx);
  const int x = jj / ppx;
  const int head = pair & (NH - 1);
  const int z = pair >> 4;

  const int qbase = x * 64 + wave * 16;
  const int Svalid = *clp + TNEW;
  const int ntiles = (Svalid + 31) >> 5;
  const int per = (ntiles + splits - 1) / splits;
  const int it0 = z * per;
  const int it1 = (ntiles < it0 + per) ? ntiles : (it0 + per);

  short8 qf[4];
#pragma unroll
  for (int kb = 0; kb < 4; kb++)
    qf[kb] = ldfrag(&qbf[((size_t)(qbase + m16) * NH + head) * HD + kb * 32 + quad * 8]);

  floatx4 O[8];
#pragma unroll
  for (int i = 0; i < 8; i++)
#pragma unroll
    for (int r = 0; r < 4; r++) O[i][r] = 0.0f;
  float mrow[4], lrow[4];
#pragma unroll
  for (int r = 0; r < 4; r++) { mrow[r] = -1e30f; lrow[r] = 0.0f; }

  const int krow = tid >> 4;
  const int ksrccol = ((tid & 15) * 16) ^ ((krow & 7) << 4);
  const char* Kbase = (const char*)(Kb + (size_t)head * MAXKV * HD);
  const int vh = tid >> 2;
  const int vs8 = (tid & 3) * 8;
  const char* Vbase = (const char*)(VbT + (size_t)head * HD * MAXKV);
  u16* myPs = &Ps[wave][0];
  const int kxor = (m16 & 7) << 4;
  const int wb = wave * 512;

  int b = 0;
  if (it0 < it1) {
    {
      const int s0 = it0 * 32;
      gload16(Kbase + ((size_t)(s0 + krow) << 8) + ksrccol,          &Ks[0][wb]);
      gload16(Kbase + ((size_t)(s0 + krow + 16) << 8) + ksrccol,     &Ks[0][2048 + wb]);
      gload16(Vbase + (((size_t)vh * MAXKV + s0 + vs8) << 1),        &Vt[0][wb]);
      gload16(Vbase + (((size_t)(vh + 64) * MAXKV + s0 + vs8) << 1), &Vt[0][2048 + wb]);
    }
    for (int it = it0; it < it1; ++it) {
      if (it + 1 < it1) {
        const int s1 = (it + 1) * 32;
        u16* KsN = &Ks[b ^ 1][0];
        u16* VtN = &Vt[b ^ 1][0];
        gload16(Kbase + ((size_t)(s1 + krow) << 8) + ksrccol,          KsN + wb);
        gload16(Kbase + ((size_t)(s1 + krow + 16) << 8) + ksrccol,     KsN + 2048 + wb);
        gload16(Vbase + (((size_t)vh * MAXKV + s1 + vs8) << 1),        VtN + wb);
        gload16(Vbase + (((size_t)(vh + 64) * MAXKV + s1 + vs8) << 1), VtN + 2048 + wb);
        asm volatile("s_waitcnt vmcnt(4) lgkmcnt(0)" ::: "memory");
      } else {
        asm volatile("s_waitcnt vmcnt(0) lgkmcnt(0)" ::: "memory");
      }
      __builtin_amdgcn_s_barrier();
      __builtin_amdgcn_sched_barrier(0);

      const u16* KsB = &Ks[b][0];
      const u16* VtB = &Vt[b][0];
      const int s0 = it * 32;

      floatx4 sc[2];
#pragma unroll
      for (int st = 0; st < 2; st++) {
        floatx4 a;
#pragma unroll
        for (int r = 0; r < 4; r++) a[r] = 0.0f;
        const int rofs = (st * 16 + m16) * 128;
#pragma unroll
        for (int kb = 0; kb < 4; kb++) {
          short8 kf = ldfrag(&KsB[rofs + (((kb * 64 + quad * 16) ^ kxor) >> 1)]);
          a = __builtin_amdgcn_mfma_f32_16x16x32_bf16(qf[kb], kf, a, 0, 0, 0);
        }
        const int scol = s0 + st * 16 + m16;
        if (scol >= Svalid) {
#pragma unroll
          for (int r = 0; r < 4; r++) a[r] = -1e30f;
        }
        sc[st] = a;
      }

      float alpha[4];
#pragma unroll
      for (int r = 0; r < 4; r++) {
        float mx = fmaxf(sc[0][r], sc[1][r]);
        mx = fmaxf(mx, __shfl_xor(mx, 1, 64));
        mx = fmaxf(mx, __shfl_xor(mx, 2, 64));
        mx = fmaxf(mx, __shfl_xor(mx, 4, 64));
        mx = fmaxf(mx, __shfl_xor(mx, 8, 64));
        const float mn = fmaxf(mrow[r], mx);
        alpha[r] = exp2f(mrow[r] - mn);
        const float p0 = exp2f(sc[0][r] - mn);
        const float p1 = exp2f(sc[1][r] - mn);
        sc[0][r] = p0; sc[1][r] = p1;
        float rs = p0 + p1;
        rs += __shfl_xor(rs, 1, 64);
        rs += __shfl_xor(rs, 2, 64);
        rs += __shfl_xor(rs, 4, 64);
        rs += __shfl_xor(rs, 8, 64);
        lrow[r] = lrow[r] * alpha[r] + rs;
        mrow[r] = mn;
      }
#pragma unroll
      for (int hb = 0; hb < 8; hb++)
#pragma unroll
        for (int r = 0; r < 4; r++) O[hb][r] *= alpha[r];

#pragma unroll
      for (int st = 0; st < 2; st++)
#pragma unroll
        for (int r = 0; r < 4; r++)
          myPs[(quad * 4 + r) * 40 + st * 16 + m16] = f2bf(sc[st][r]);
      short8 pfr = ldfrag(&myPs[m16 * 40 + quad * 8]);
#pragma unroll
      for (int hb = 0; hb < 8; hb++) {
        short8 vf = ldfrag(&VtB[(hb * 16 + m16) * 32 + quad * 8]);
        O[hb] = __builtin_amdgcn_mfma_f32_16x16x32_bf16(pfr, vf, O[hb], 0, 0, 0);
      }

      asm volatile("s_waitcnt lgkmcnt(0)" ::: "memory");
      __builtin_amdgcn_s_barrier();
      __builtin_amdgcn_sched_barrier(0);
      b ^= 1;
    }
  }

  const size_t zbase = (size_t)z * TN * NH;
  const int trow = qbase + quad * 4;
#pragma unroll
  for (int hb = 0; hb < 8; hb++)
#pragma unroll
    for (int r = 0; r < 4; r++)
      Opart[(zbase + (size_t)(trow + r) * NH + head) * HD + hb * 16 + m16] = O[hb][r];
  if (m16 == 0) {
#pragma unroll
    for (int r = 0; r < 4; r++) {
      Oml[(zbase + (size_t)(trow + r) * NH + head) * 2 + 0] = mrow[r];
      Oml[(zbase + (size_t)(trow + r) * NH + head) * 2 + 1] = lrow[r];
    }
  }
}

// ============================================================================
// 6-legacy) fallback attention reading f32 caches (used if ws too small)
// ============================================================================
__global__ __launch_bounds__(256) void attn_k(
    const u16* __restrict__ qbf, const float* __restrict__ outK,
    const float* __restrict__ outV, const int* __restrict__ clp,
    float* __restrict__ Opart, float* __restrict__ Oml)
{
  __shared__ u16 Ksl[32 * 136];
  __shared__ u16 Vtl[128 * 40];
  __shared__ u16 Psl[4 * 16 * 40];
  const int tid = threadIdx.x;
  const int lane = tid & 63, wave = tid >> 6;
  const int quad = lane >> 4, m16 = lane & 15;
  const int head = blockIdx.y;
  const int qbase = blockIdx.x * 64 + wave * 16;
  const int z = blockIdx.z, splits = gridDim.z;
  const int Svalid = *clp + TNEW;
  const int ntiles = (Svalid + 31) >> 5;
  const int per = (ntiles + splits - 1) / splits;
  const int it0 = z * per;
  const int it1 = min(ntiles, it0 + per);

  short8 qf[4];
#pragma unroll
  for (int kb = 0; kb < 4; kb++)
    qf[kb] = ldfrag(&qbf[((size_t)(qbase + m16) * NH + head) * HD + kb * 32 + quad * 8]);

  floatx4 O[8];
#pragma unroll
  for (int i = 0; i < 8; i++)
#pragma unroll
    for (int r = 0; r < 4; r++) O[i][r] = 0.0f;
  float mrow[4], lrow[4];
#pragma unroll
  for (int r = 0; r < 4; r++) { mrow[r] = -1e30f; lrow[r] = 0.0f; }

  const int sstage = tid >> 3;
  const int hg = (tid & 7) * 16;

  for (int it = it0; it < it1; it++) {
    const int s0 = it * 32;
    {
      int srow = s0 + sstage; if (srow > MAXKV - 1) srow = MAXKV - 1;
      const float* kp = outK + ((size_t)head * MAXKV + srow) * HD + hg;
      float tv[16];
      *(float4*)(tv)      = *(const float4*)(kp);
      *(float4*)(tv + 4)  = *(const float4*)(kp + 4);
      *(float4*)(tv + 8)  = *(const float4*)(kp + 8);
      *(float4*)(tv + 12) = *(const float4*)(kp + 12);
      *(uint4*)&Ksl[sstage * 136 + hg]     = pack8(tv);
      *(uint4*)&Ksl[sstage * 136 + hg + 8] = pack8(tv + 8);
      const float* vp = outV + ((size_t)head * MAXKV + srow) * HD + hg;
      float vv[16];
      *(float4*)(vv)      = *(const float4*)(vp);
      *(float4*)(vv + 4)  = *(const float4*)(vp + 4);
      *(float4*)(vv + 8)  = *(const float4*)(vp + 8);
      *(float4*)(vv + 12) = *(const float4*)(vp + 12);
#pragma unroll
      for (int j = 0; j < 16; j++) Vtl[(hg + j) * 40 + sstage] = f2bf(vv[j]);
    }
    __syncthreads();

    floatx4 sc[2];
#pragma unroll
    for (int st = 0; st < 2; st++) {
      floatx4 a;
#pragma unroll
      for (int r = 0; r < 4; r++) a[r] = 0.0f;
#pragma unroll
      for (int kb = 0; kb < 4; kb++) {
        short8 kf = ldfrag(&Ksl[(st * 16 + m16) * 136 + kb * 32 + quad * 8]);
        a = __builtin_amdgcn_mfma_f32_16x16x32_bf16(qf[kb], kf, a, 0, 0, 0);
      }
      const int scol = s0 + st * 16 + m16;
      if (scol >= Svalid) {
#pragma unroll
        for (int r = 0; r < 4; r++) a[r] = -1e30f;
      }
      sc[st] = a;
    }

    float alpha[4];
#pragma unroll
    for (int r = 0; r < 4; r++) {
      float mx = fmaxf(sc[0][r], sc[1][r]);
      mx = fmaxf(mx, __shfl_xor(mx, 1, 64));
      mx = fmaxf(mx, __shfl_xor(mx, 2, 64));
      mx = fmaxf(mx, __shfl_xor(mx, 4, 64));
      mx = fmaxf(mx, __shfl_xor(mx, 8, 64));
      const float mn = fmaxf(mrow[r], mx);
      alpha[r] = exp2f(mrow[r] - mn);
      const float p0 = exp2f(sc[0][r] - mn);
      const float p1 = exp2f(sc[1][r] - mn);
      sc[0][r] = p0; sc[1][r] = p1;
      float rs = p0 + p1;
      rs += __shfl_xor(rs, 1, 64);
      rs += __shfl_xor(rs, 2, 64);
      rs += __shfl_xor(rs, 4, 64);
      rs += __shfl_xor(rs, 8, 64);
      lrow[r] = lrow[r] * alpha[r] + rs;
      mrow[r] = mn;
    }
#pragma unroll
    for (int hb = 0; hb < 8; hb++)
#pragma unroll
      for (int r = 0; r < 4; r++) O[hb][r] *= alpha[r];

    u16* myPs = &Psl[wave * 640];
#pragma unroll
    for (int st = 0; st < 2; st++)
#pragma unroll
      for (int r = 0; r < 4; r++)
        myPs[(quad * 4 + r) * 40 + st * 16 + m16] = f2bf(sc[st][r]);
    short8 pf = ldfrag(&myPs[m16 * 40 + quad * 8]);
#pragma unroll
    for (int hb = 0; hb < 8; hb++) {
      short8 vf = ldfrag(&Vtl[(hb * 16 + m16) * 40 + quad * 8]);
      O[hb] = __builtin_amdgcn_mfma_f32_16x16x32_bf16(pf, vf, O[hb], 0, 0, 0);
    }
    __syncthreads();
  }

  const size_t zbase = (size_t)z * TN * NH;
  const int trow = qbase + quad * 4;
#pragma unroll
  for (int hb = 0; hb < 8; hb++)
#pragma unroll
    for (int r = 0; r < 4; r++)
      Opart[(zbase + (size_t)(trow + r) * NH + head) * HD + hb * 16 + m16] = O[hb][r];
  if (m16 == 0) {
#pragma unroll
    for (int r = 0; r < 4; r++) {
      Oml[(zbase + (size_t)(trow + r) * NH + head) * 2 + 0] = mrow[r];
      Oml[(zbase + (size_t)(trow + r) * NH + head) * 2 + 1] = lrow[r];
    }
  }
}

// ============================================================================
// 6b) combine split-S partials -> attnb (f32) and attnbf (bf16)
// ============================================================================
__global__ __launch_bounds__(128) void attn_combine(
    const float* __restrict__ Opart, const float* __restrict__ Oml,
    float* __restrict__ attnb, u16* __restrict__ attnbf, int splits)
{
  const int pair = blockIdx.x;   // t*NH + head
  const int h = threadIdx.x;
  float M = -1e30f;
  for (int zz = 0; zz < splits; zz++)
    M = fmaxf(M, Oml[((size_t)zz * TN * NH + pair) * 2]);
  float l = 0.0f, o = 0.0f;
  for (int zz = 0; zz < splits; zz++) {
    const float mi = Oml[((size_t)zz * TN * NH + pair) * 2];
    const float li = Oml[((size_t)zz * TN * NH + pair) * 2 + 1];
    const float w = exp2f(mi - M);
    l += li * w;
    o += Opart[((size_t)zz * TN * NH + pair) * HD + h] * w;
  }
  const float res = o / l;
  attnb[(size_t)pair * HD + h] = res;
  if (attnbf) attnbf[(size_t)pair * HD + h] = f2bf(res);
}

// ============================================================================
// launch
// ============================================================================
extern "C" void kernel_launch(void* const* d_in, const int* in_sizes, int n_in,
                              void* d_out, int out_size, void* d_ws, size_t ws_size,
                              hipStream_t stream) {
  const float* x_noise       = (const float*)d_in[0];
  const float* target_hidden = (const float*)d_in[1];
  const int*   noise_pos     = (const int*)d_in[2];
  const int*   ctx_pos       = (const int*)d_in[3];
  const float* inK           = (const float*)d_in[4];
  const float* inV           = (const float*)d_in[5];
  const int*   cache_len     = (const int*)d_in[6];
  const float* wq            = (const float*)d_in[7];
  const float* wk            = (const float*)d_in[8];
  const float* wv            = (const float*)d_in[9];
  const float* wo            = (const float*)d_in[10];
  const float* q_scale       = (const float*)d_in[11];
  const float* k_scale       = (const float*)d_in[12];

  float* out0 = (float*)d_out;
  float* outK = out0 + (size_t)TN * HIDDEN;
  float* outV = outK + (size_t)NH * MAXKV * HD;

  // ---- workspace layout ----
  size_t off = 0;
  auto walloc = [&](size_t bytes) -> void* {
    void* p = (char*)d_ws + off;
    off += (bytes + 255) & ~(size_t)255;
    return p;
  };
  u16*   qbf    = (u16*)walloc((size_t)TN * HIDDEN * 2);
  float* attnb  = (float*)walloc((size_t)TN * HIDDEN * 4);
  u16*   attnbf = (u16*)walloc((size_t)TN * HIDDEN * 2);
  float* qproj  = (float*)walloc((size_t)TN * HIDDEN * 4);
  float* kproj  = (float*)walloc((size_t)TNEW * NKV * HD * 4);
  float* vproj  = (float*)walloc((size_t)TNEW * NKV * HD * 4);

  const size_t PER_SPLIT = (size_t)TN * NH * HD * 4 + (size_t)TN * NH * 8;
  const size_t SHB   = (size_t)NH * MAXKV * HD * sizeof(u16);   // 32 MB each
  const size_t GPART = (size_t)4 * TN * HIDDEN * 4;             // 16 MB
  // convert/transpose buffers: xbf + thbf + wqT + wkT + wvT + woT
  const size_t CONVB = ((size_t)TN * HIDDEN + (size_t)TC * HIDDEN) * 2
                     + ((size_t)HIDDEN * HIDDEN * 2                 // wqT, woT
                      + (size_t)HIDDEN * (NKV * HD) * 2) * 2;       // wkT, wvT
  auto maxsz = [](size_t a, size_t b) { return a > b ? a : b; };

  size_t avail = (ws_size > off) ? ws_size - off : 0;
  bool conv = false;
  int asplits = 0;
  if (avail >= CONVB + 2 * SHB + maxsz(8 * PER_SPLIT, GPART))      { conv = true; asplits = 8; }
  else if (avail >= CONVB + 2 * SHB + maxsz(4 * PER_SPLIT, GPART)) { conv = true; asplits = 4; }
  else if (avail >= 2 * SHB + maxsz(8 * PER_SPLIT, GPART))         { asplits = 8; }
  else if (avail >= 2 * SHB + maxsz(4 * PER_SPLIT, GPART))         { asplits = 4; }
  const bool shadow = (asplits > 0);

  u16 *xbf = nullptr, *thbf = nullptr, *wqT = nullptr, *wkT = nullptr,
      *wvT = nullptr, *woT = nullptr;
  if (conv) {
    xbf  = (u16*)walloc((size_t)TN * HIDDEN * 2);
    thbf = (u16*)walloc((size_t)TC * HIDDEN * 2);
    wqT  = (u16*)walloc((size_t)HIDDEN * HIDDEN * 2);
    wkT  = (u16*)walloc((size_t)HIDDEN * (NKV * HD) * 2);
    wvT  = (u16*)walloc((size_t)HIDDEN * (NKV * HD) * 2);
    woT  = (u16*)walloc((size_t)HIDDEN * HIDDEN * 2);
  }
  u16 *Kb = nullptr, *VbT = nullptr;
  if (shadow) {
    Kb  = (u16*)walloc(SHB);
    VbT = (u16*)walloc(SHB);
  }

  float* scratch = (float*)((char*)d_ws + off);
  const size_t avail2 = (ws_size > off) ? ws_size - off : 0;
  if (!shadow) {
    asplits = 2;
    if (avail2 >= 8 * PER_SPLIT) asplits = 8;
    else if (avail2 >= 4 * PER_SPLIT) asplits = 4;
  }
  float* Opart = scratch;
  float* Oml   = Opart + (size_t)asplits * TN * NH * HD;
  const bool ksplit = (avail2 >= GPART);
  float* gpart = scratch;   // shared with Opart (phases don't overlap)

  if (conv) {
    conv_bf16<<<dim3((TN * HIDDEN / 4 + 255) / 256), dim3(256), 0, stream>>>(
        (const float4*)x_noise, (uint2*)xbf, TN * HIDDEN / 4);
    conv_bf16<<<dim3((TC * HIDDEN / 4 + 255) / 256), dim3(256), 0, stream>>>(
        (const float4*)target_hidden, (uint2*)thbf, TC * HIDDEN / 4);
    transpose_bf16<<<dim3(HIDDEN / 64, HIDDEN / 64), dim3(256), 0, stream>>>(
        wq, wqT, HIDDEN, HIDDEN);
    transpose_bf16<<<dim3(NKV * HD / 64, HIDDEN / 64), dim3(256), 0, stream>>>(
        wk, wkT, HIDDEN, NKV * HD);
    transpose_bf16<<<dim3(NKV * HD / 64, HIDDEN / 64), dim3(256), 0, stream>>>(
        wv, wvT, HIDDEN, NKV * HD);
    transpose_bf16<<<dim3(HIDDEN / 64, HIDDEN / 64), dim3(256), 0, stream>>>(
        wo, woT, NH * HD, HIDDEN);
  }

  cache_copy<<<dim3(32768), dim3(256), 0, stream>>>(
      (const float4*)inK, (const float4*)inV, (float4*)outK, (float4*)outV,
      cache_len, Kb, VbT);

  // Q projection
  if (conv && ksplit) {
    gemm_v2<<<dim3(HIDDEN / 128, TN / 128, 4), dim3(256), 0, stream>>>(
        xbf, TN, xbf, wqT, wqT, HIDDEN, gpart, gpart, TN, HIDDEN, HIDDEN, 16);
    reduce4<<<dim3((TN * HIDDEN / 4 + 255) / 256), dim3(256), 0, stream>>>(
        (const float4*)gpart, (float4*)qproj, TN * HIDDEN / 4);
  } else if (conv) {
    gemm_v2<<<dim3(HIDDEN / 128, TN / 128, 1), dim3(256), 0, stream>>>(
        xbf, TN, xbf, wqT, wqT, HIDDEN, qproj, qproj, TN, HIDDEN, HIDDEN, 64);
  } else if (ksplit) {
    gemm_bf16<<<dim3(HIDDEN / 64, TN / 64, 4), dim3(256), 0, stream>>>(
        x_noise, TN, x_noise, wq, wq, HIDDEN, gpart, gpart, TN, HIDDEN, HIDDEN, 16);
    reduce4<<<dim3((TN * HIDDEN / 4 + 255) / 256), dim3(256), 0, stream>>>(
        (const float4*)gpart, (float4*)qproj, TN * HIDDEN / 4);
  } else {
    gemm_bf16<<<dim3(HIDDEN / 64, TN / 64, 1), dim3(256), 0, stream>>>(
        x_noise, TN, x_noise, wq, wq, HIDDEN, qproj, qproj, TN, HIDDEN, HIDDEN, 64);
  }

  // merged K+V projection
  if (conv) {
    gemm_v2<<<dim3(2 * NKV * HD / 128, TNEW / 128, 1), dim3(256), 0, stream>>>(
        thbf, TC, xbf, wkT, wvT, NKV * HD, kproj, vproj,
        TNEW, 2 * NKV * HD, HIDDEN, 64);
  } else {
    gemm_bf16<<<dim3(2 * NKV * HD / 64, TNEW / 64, 1), dim3(256), 0, stream>>>(
        target_hidden, TC, x_noise, wk, wv, NKV * HD, kproj, vproj,
        TNEW, 2 * NKV * HD, HIDDEN, 64);
  }

  q_post_k<<<dim3(TN, NH), dim3(64), 0, stream>>>(qproj, noise_pos, q_scale, qbf);
  k_post_k<<<dim3(TNEW, NKV), dim3(64), 0, stream>>>(
      kproj, ctx_pos, noise_pos, k_scale, cache_len, outK, Kb);
  v_post_k<<<dim3(TNEW, NKV), dim3(128), 0, stream>>>(vproj, cache_len, outV, VbT);

  if (shadow) {
    attn_sh<<<dim3((TN / 64) * NH * asplits), dim3(256), 0, stream>>>(
        qbf, Kb, VbT, cache_len, Opart, Oml, asplits);
  } else {
    attn_k<<<dim3(TN / 64, NH, asplits), dim3(256), 0, stream>>>(
        qbf, outK, outV, cache_len, Opart, Oml);
  }
  attn_combine<<<dim3(TN * NH), dim3(128), 0, stream>>>(
      Opart, Oml, attnb, conv ? attnbf : nullptr, asplits);

  // output projection
  if (conv && ksplit) {
    gemm_v2<<<dim3(HIDDEN / 128, TN / 128, 4), dim3(256), 0, stream>>>(
        attnbf, TN, attnbf, woT, woT, HIDDEN, gpart, gpart, TN, HIDDEN, HIDDEN, 16);
    reduce4<<<dim3((TN * HIDDEN / 4 + 255) / 256), dim3(256), 0, stream>>>(
        (const float4*)gpart, (float4*)out0, TN * HIDDEN / 4);
  } else if (conv) {
    gemm_v2<<<dim3(HIDDEN / 128, TN / 128, 1), dim3(256), 0, stream>>>(
        attnbf, TN, attnbf, woT, woT, HIDDEN, out0, out0, TN, HIDDEN, HIDDEN, 64);
  } else if (ksplit) {
    gemm_bf16<<<dim3(HIDDEN / 64, TN / 64, 4), dim3(256), 0, stream>>>(
        attnb, TN, attnb, wo, wo, HIDDEN, gpart, gpart, TN, HIDDEN, HIDDEN, 16);
    reduce4<<<dim3((TN * HIDDEN / 4 + 255) / 256), dim3(256), 0, stream>>>(
        (const float4*)gpart, (float4*)out0, TN * HIDDEN / 4);
  } else {
    gemm_bf16<<<dim3(HIDDEN / 64, TN / 64, 1), dim3(256), 0, stream>>>(
        attnb, TN, attnb, wo, wo, HIDDEN, out0, out0, TN, HIDDEN, HIDDEN, 64);
  }
}

// Round 4
// 469.652 us; speedup vs baseline: 1.2042x; 1.1261x over previous
//
#include <hip/hip_runtime.h>
#include <hip/hip_bf16.h>

// ---- problem constants ----
#define HIDDEN 2048
#define NH 16
#define NKV 8
#define HD 128
#define TN 512      // T_NOISE
#define TC 1536     // T_CTX
#define TNEW 2048   // TC + TN
#define MAXKV 8192

using u16 = unsigned short;
using u32 = unsigned int;

typedef short short8 __attribute__((ext_vector_type(8)));
typedef float floatx4 __attribute__((ext_vector_type(4)));

__device__ __forceinline__ u16 f2bf(float f) {
  u32 u = __float_as_uint(f);
  u += 0x7FFFu + ((u >> 16) & 1u);   // round-to-nearest-even
  return (u16)(u >> 16);
}

__device__ __forceinline__ uint4 pack8(const float* f) {
  uint4 r;
  r.x = (u32)f2bf(f[0]) | ((u32)f2bf(f[1]) << 16);
  r.y = (u32)f2bf(f[2]) | ((u32)f2bf(f[3]) << 16);
  r.z = (u32)f2bf(f[4]) | ((u32)f2bf(f[5]) << 16);
  r.w = (u32)f2bf(f[6]) | ((u32)f2bf(f[7]) << 16);
  return r;
}

__device__ __forceinline__ short8 ldfrag(const u16* p) {
  uint4 v = *(const uint4*)p;
  return __builtin_bit_cast(short8, v);
}

// async global->LDS, 16B per lane.
// l MUST be wave-uniform: HW writes lane i's 16B at l + i*16.
__device__ __forceinline__ void gload16(const void* g, void* l) {
  __builtin_amdgcn_global_load_lds(
      (const __attribute__((address_space(1))) u32*)g,
      (__attribute__((address_space(3))) u32*)l, 16, 0, 0);
}

// ============================================================================
// 0a) f32 -> bf16 convert (vectorized)
// ============================================================================
__global__ __launch_bounds__(256) void conv_bf16(
    const float4* __restrict__ in, uint2* __restrict__ out, int n4)
{
  int idx = blockIdx.x * 256 + threadIdx.x;
  if (idx >= n4) return;
  float4 v = in[idx];
  uint2 r;
  r.x = (u32)f2bf(v.x) | ((u32)f2bf(v.y) << 16);
  r.y = (u32)f2bf(v.z) | ((u32)f2bf(v.w) << 16);
  out[idx] = r;
}

// ============================================================================
// 0b) f32 [K][N] -> bf16 [N][K] transpose (LDS-tiled 64x64)
// ============================================================================
__global__ __launch_bounds__(256) void transpose_bf16(
    const float* __restrict__ w, u16* __restrict__ wT, int K, int N)
{
  __shared__ float t[64][65];
  const int bk = blockIdx.y * 64, bn = blockIdx.x * 64;
  const int tid = threadIdx.x;
  const int r = tid >> 4, c4 = (tid & 15) * 4;
#pragma unroll
  for (int rr = 0; rr < 4; rr++) {
    float4 v = *(const float4*)(w + (size_t)(bk + rr * 16 + r) * N + bn + c4);
    t[rr * 16 + r][c4 + 0] = v.x;
    t[rr * 16 + r][c4 + 1] = v.y;
    t[rr * 16 + r][c4 + 2] = v.z;
    t[rr * 16 + r][c4 + 3] = v.w;
  }
  __syncthreads();
  const int n = tid >> 2, k16 = (tid & 3) * 16;
  u32 wbuf[8];
#pragma unroll
  for (int jj = 0; jj < 8; jj++) {
    float lo = t[k16 + 2 * jj][n], hi = t[k16 + 2 * jj + 1][n];
    wbuf[jj] = (u32)f2bf(lo) | ((u32)f2bf(hi) << 16);
  }
  *(uint4*)(&wT[(size_t)(bn + n) * K + bk + k16])     = *(uint4*)(wbuf);
  *(uint4*)(&wT[(size_t)(bn + n) * K + bk + k16 + 8]) = *(uint4*)(wbuf + 4);
}

// ============================================================================
// 0c) Build VbT[head][h][s] bf16 from inV (s < cl) / vproj (cl <= s < cl+TNEW)
//     LDS-tiled 64s x 64h per block: coalesced reads, 128B-run writes.
//     Replaces the old 2B-at-16KB-stride scatter (write amplification).
// ============================================================================
__global__ __launch_bounds__(256) void vT_build(
    const float* __restrict__ inV, const float* __restrict__ vproj,
    const int* __restrict__ clp, u16* __restrict__ VbT)
{
  __shared__ float t[64][65];
  const int cl = *clp;
  const int s0 = blockIdx.x * 64;
  const int slim = cl + TNEW;
  if (s0 >= slim) return;                  // rows never read by attention
  const int h0 = blockIdx.y * 64;
  const int head = blockIdx.z;
  const int tid = threadIdx.x;

  const int rr = tid >> 2, c16 = (tid & 3) * 16;
  int s = s0 + rr;
  if (s >= slim) s = slim - 1;             // clamp (dup row, unread)
  const float* src = (s < cl)
      ? inV + ((size_t)head * MAXKV + s) * HD + (h0 + c16)
      : vproj + (size_t)(s - cl) * (NKV * HD) + (head >> 1) * HD + (h0 + c16);
  float4 v0 = ((const float4*)src)[0];
  float4 v1 = ((const float4*)src)[1];
  float4 v2 = ((const float4*)src)[2];
  float4 v3 = ((const float4*)src)[3];
  *(float4*)&t[rr][c16 + 0]  = v0;
  *(float4*)&t[rr][c16 + 4]  = v1;
  *(float4*)&t[rr][c16 + 8]  = v2;
  *(float4*)&t[rr][c16 + 12] = v3;
  __syncthreads();

  const int hh = tid >> 2, sseg = (tid & 3) * 16;
  u32 wbuf[8];
#pragma unroll
  for (int j = 0; j < 8; j++)
    wbuf[j] = (u32)f2bf(t[sseg + 2 * j][hh]) | ((u32)f2bf(t[sseg + 2 * j + 1][hh]) << 16);
  u16* dst = VbT + ((size_t)head * HD + h0 + hh) * MAXKV + s0 + sseg;
  *(uint4*)(dst)     = *(uint4*)(wbuf);
  *(uint4*)(dst + 8) = *(uint4*)(wbuf + 4);
}

// ============================================================================
// 1) Copy kv caches to output, skipping the scatter window. Also emits bf16
//    K shadow Kb[head][s][h] (coalesced). V shadow handled by vT_build.
// ============================================================================
__global__ __launch_bounds__(256) void cache_copy(
    const float4* __restrict__ inK, const float4* __restrict__ inV,
    float4* __restrict__ outK, float4* __restrict__ outV,
    const int* __restrict__ clp, u16* __restrict__ Kb)
{
  const int cl = *clp;
  long long idx = (long long)blockIdx.x * 256 + threadIdx.x;
  const long long per = (long long)NH * MAXKV * (HD / 4);   // 4,194,304
  const float4* src; float4* dst; bool isv;
  long long r = idx;
  if (r < per) { src = inK; dst = outK; isv = false; }
  else { r -= per; src = inV; dst = outV; isv = true; }
  int row = (int)((r >> 5) & (MAXKV - 1));  // s index within a head
  if (row >= cl && row < cl + TNEW) return; // will be written by scatter
  float4 v = src[r];
  dst[r] = v;
  if (!isv && row < cl && Kb) {
    uint2 p;
    p.x = (u32)f2bf(v.x) | ((u32)f2bf(v.y) << 16);
    p.y = (u32)f2bf(v.z) | ((u32)f2bf(v.w) << 16);
    *(uint2*)(Kb + (size_t)r * 4) = p;
  }
}

// ============================================================================
// 2) GEMM: bf16 A [M][K], bf16 B^T [N][K], f32 C. 128x128 tile, BK=32,
//    4 waves (2x2). global_load_lds staging, double-buffered, counted vmcnt.
// ============================================================================
__global__ __launch_bounds__(256) void gemm_v2(
    const u16* __restrict__ A0, int rows0, const u16* __restrict__ A1,
    const u16* __restrict__ B0, const u16* __restrict__ B1, int Nhalf,
    float* __restrict__ C0, float* __restrict__ C1,
    int M, int N, int K, int ksteps)
{
  __shared__ u16 As[2][128 * 32];
  __shared__ u16 Bs[2][128 * 32];
  const int tid = threadIdx.x;
  const int lane = tid & 63, wave = tid >> 6;
  const int quad = lane >> 4, m16 = lane & 15;

  const int gx = gridDim.x, gy = gridDim.y;
  int bx = blockIdx.x, by = blockIdx.y;
  if (((gx & 3) == 0) && ((gy & 1) == 0)) {
    const int lin = bx + gx * by;
    const int c = lin & 7, j = lin >> 3;
    const int sw = gx >> 2, sh = gy >> 1;
    bx = (c & 3) * sw + j % sw;
    by = (c >> 2) * sh + j / sw;
  }
  const int bm = by * 128, bn = bx * 128;
  const int wm = (wave >> 1) * 64, wn = (wave & 1) * 64;
  const int z = blockIdx.z;
  const int kbase = z * ksteps * 32;

  const u16* B = (bn < Nhalf) ? B0 : B1;
  float*     C = (bn < Nhalf) ? C0 : C1;
  const int n0 = (bn < Nhalf) ? bn : bn - Nhalf;
  const int strideN = (bn < Nhalf) ? Nhalf : (N - Nhalf);

  floatx4 acc[4][4];
#pragma unroll
  for (int i = 0; i < 4; i++)
#pragma unroll
    for (int j = 0; j < 4; j++)
#pragma unroll
      for (int r = 0; r < 4; r++) acc[i][j][r] = 0.0f;

  const int srow = tid >> 2;
  const int sk = (tid & 3) * 8;
  const int ar0 = bm + srow, ar1 = bm + srow + 64;
  const u16* Arow0 = (ar0 < rows0) ? (A0 + (size_t)ar0 * K)
                                   : (A1 + (size_t)(ar0 - rows0) * K);
  const u16* Arow1 = (ar1 < rows0) ? (A0 + (size_t)ar1 * K)
                                   : (A1 + (size_t)(ar1 - rows0) * K);
  const u16* Brow0 = B + (size_t)(n0 + srow) * K;
  const u16* Brow1 = B + (size_t)(n0 + srow + 64) * K;
  const int wb = wave * 512;

  {
    const int k0 = kbase;
    gload16(Arow0 + k0 + sk, &As[0][wb]);
    gload16(Arow1 + k0 + sk, &As[0][2048 + wb]);
    gload16(Brow0 + k0 + sk, &Bs[0][wb]);
    gload16(Brow1 + k0 + sk, &Bs[0][2048 + wb]);
  }
  int b = 0;
  for (int ks = 0; ks < ksteps; ks++) {
    if (ks + 1 < ksteps) {
      const int k1 = kbase + (ks + 1) * 32;
      gload16(Arow0 + k1 + sk, &As[b ^ 1][wb]);
      gload16(Arow1 + k1 + sk, &As[b ^ 1][2048 + wb]);
      gload16(Brow0 + k1 + sk, &Bs[b ^ 1][wb]);
      gload16(Brow1 + k1 + sk, &Bs[b ^ 1][2048 + wb]);
      asm volatile("s_waitcnt vmcnt(4)" ::: "memory");
    } else {
      asm volatile("s_waitcnt vmcnt(0)" ::: "memory");
    }
    __builtin_amdgcn_s_barrier();
    __builtin_amdgcn_sched_barrier(0);

    short8 af[4], bfr[4];
#pragma unroll
    for (int i = 0; i < 4; i++) {
      af[i]  = ldfrag(&As[b][(wm + i * 16 + m16) * 32 + quad * 8]);
      bfr[i] = ldfrag(&Bs[b][(wn + i * 16 + m16) * 32 + quad * 8]);
    }
#pragma unroll
    for (int i = 0; i < 4; i++)
#pragma unroll
      for (int j = 0; j < 4; j++)
        acc[i][j] = __builtin_amdgcn_mfma_f32_16x16x32_bf16(af[i], bfr[j], acc[i][j], 0, 0, 0);

    asm volatile("s_waitcnt lgkmcnt(0)" ::: "memory");
    __builtin_amdgcn_s_barrier();
    __builtin_amdgcn_sched_barrier(0);
    b ^= 1;
  }

  const size_t zoff = (size_t)z * M * Nhalf;
#pragma unroll
  for (int i = 0; i < 4; i++)
#pragma unroll
    for (int j = 0; j < 4; j++)
#pragma unroll
      for (int r = 0; r < 4; r++) {
        int row = bm + wm + i * 16 + quad * 4 + r;
        int col = wn + j * 16 + m16;
        C[zoff + (size_t)row * strideN + n0 + col] = acc[i][j][r];
      }
}

// ============================================================================
// 2-legacy) f32-input GEMM (fallback when workspace too small for converts)
// ============================================================================
__global__ __launch_bounds__(256) void gemm_bf16(
    const float* __restrict__ A0, int rows0, const float* __restrict__ A1,
    const float* __restrict__ B0, const float* __restrict__ B1, int Nhalf,
    float* __restrict__ C0, float* __restrict__ C1,
    int M, int N, int K, int ksteps)
{
  __shared__ u16 As[64 * 40];
  __shared__ u16 Bs[64 * 40];
  const int tid = threadIdx.x;
  const int lane = tid & 63;
  const int wave = tid >> 6;
  const int quad = lane >> 4;
  const int m16 = lane & 15;
  const int bm = blockIdx.y * 64;
  const int bn = blockIdx.x * 64;
  const int wm = (wave >> 1) * 32;
  const int wn = (wave & 1) * 32;
  const int z = blockIdx.z;
  const int kbase = z * ksteps * 32;

  const float* B = (bn < Nhalf) ? B0 : B1;
  float*       C = (bn < Nhalf) ? C0 : C1;
  const int n0 = (bn < Nhalf) ? bn : bn - Nhalf;
  const int strideN = (bn < Nhalf) ? Nhalf : (N - Nhalf);

  floatx4 acc[2][2];
#pragma unroll
  for (int i = 0; i < 2; i++)
#pragma unroll
    for (int j = 0; j < 2; j++)
#pragma unroll
      for (int r = 0; r < 4; r++) acc[i][j][r] = 0.0f;

  const int arow = tid >> 2, akg = (tid & 3) * 8;
  const int brow = tid >> 3, bng = (tid & 7) * 8;
  const int garow = bm + arow;
  const float* Ap = (garow < rows0) ? (A0 + (size_t)garow * K)
                                    : (A1 + (size_t)(garow - rows0) * K);

  for (int ks = 0; ks < ksteps; ks++) {
    const int k0 = kbase + ks * 32;
    if (k0 >= K) break;
    float av[8];
    *(float4*)(av)     = *(const float4*)(Ap + k0 + akg);
    *(float4*)(av + 4) = *(const float4*)(Ap + k0 + akg + 4);
    *(uint4*)&As[arow * 40 + akg] = pack8(av);

    float bv[8];
    const float* Bp = B + (size_t)(k0 + brow) * strideN + n0 + bng;
    *(float4*)(bv)     = *(const float4*)(Bp);
    *(float4*)(bv + 4) = *(const float4*)(Bp + 4);
#pragma unroll
    for (int j = 0; j < 8; j++) Bs[(bng + j) * 40 + brow] = f2bf(bv[j]);

    __syncthreads();

    short8 a0 = ldfrag(&As[(wm + m16) * 40 + quad * 8]);
    short8 a1 = ldfrag(&As[(wm + 16 + m16) * 40 + quad * 8]);
    short8 b0 = ldfrag(&Bs[(wn + m16) * 40 + quad * 8]);
    short8 b1 = ldfrag(&Bs[(wn + 16 + m16) * 40 + quad * 8]);
    acc[0][0] = __builtin_amdgcn_mfma_f32_16x16x32_bf16(a0, b0, acc[0][0], 0, 0, 0);
    acc[0][1] = __builtin_amdgcn_mfma_f32_16x16x32_bf16(a0, b1, acc[0][1], 0, 0, 0);
    acc[1][0] = __builtin_amdgcn_mfma_f32_16x16x32_bf16(a1, b0, acc[1][0], 0, 0, 0);
    acc[1][1] = __builtin_amdgcn_mfma_f32_16x16x32_bf16(a1, b1, acc[1][1], 0, 0, 0);

    __syncthreads();
  }

  const size_t zoff = (size_t)z * M * Nhalf;
#pragma unroll
  for (int mt = 0; mt < 2; mt++)
#pragma unroll
    for (int nt = 0; nt < 2; nt++)
#pragma unroll
      for (int r = 0; r < 4; r++) {
        int row = bm + wm + mt * 16 + quad * 4 + r;
        int col = wn + nt * 16 + m16;
        C[zoff + (size_t)row * strideN + n0 + col] = acc[mt][nt][r];
      }
}

// ============================================================================
// 2b) reduce 4 split-K partials: C = sum_z P[z]
// ============================================================================
__global__ __launch_bounds__(256) void reduce4(
    const float4* __restrict__ P, float4* __restrict__ C, int n4)
{
  int idx = blockIdx.x * 256 + threadIdx.x;
  if (idx >= n4) return;
  float4 a = P[idx], b = P[idx + n4], c = P[idx + 2 * n4], d = P[idx + 3 * n4];
  float4 r;
  r.x = (a.x + b.x) + (c.x + d.x);
  r.y = (a.y + b.y) + (c.y + d.y);
  r.z = (a.z + b.z) + (c.z + d.z);
  r.w = (a.w + b.w) + (c.w + d.w);
  C[idx] = r;
}

// ============================================================================
// 3) Q post: RMSNorm(q_scale) + RoPE + fold sm_scale*log2e, emit bf16
// ============================================================================
__global__ __launch_bounds__(64) void q_post_k(
    const float* __restrict__ qproj, const int* __restrict__ npos,
    const float* __restrict__ qscale, u16* __restrict__ qbf)
{
  const int t = blockIdx.x, n = blockIdx.y, i = threadIdx.x;
  const size_t base = (size_t)t * HIDDEN + n * HD;
  const float x1 = qproj[base + i];
  const float x2 = qproj[base + i + 64];
  float ss = x1 * x1 + x2 * x2;
#pragma unroll
  for (int m = 1; m < 64; m <<= 1) ss += __shfl_xor(ss, m, 64);
  const float rstd = rsqrtf(ss * (1.0f / HD) + 1e-6f);
  float y1 = x1 * rstd * qscale[i];
  float y2 = x2 * rstd * qscale[i + 64];
  const float pos = (float)npos[t];
  const float ang = pos * exp2f(-(float)i * (19.931568569324174f / 64.0f));
  const float c = cosf(ang), s = sinf(ang);
  const float sc = 0.08838834764831845f * 1.4426950408889634f;  // sm_scale*log2e
  qbf[base + i]      = f2bf((y1 * c - y2 * s) * sc);
  qbf[base + i + 64] = f2bf((y2 * c + y1 * s) * sc);
}

// ============================================================================
// 4) K post: RMSNorm(k_scale) + RoPE, scatter f32 into out cache (GQA repeat)
//    + bf16 shadow Kb[head][s][h]
// ============================================================================
__global__ __launch_bounds__(64) void k_post_k(
    const float* __restrict__ kproj, const int* __restrict__ ctxpos,
    const int* __restrict__ npos, const float* __restrict__ kscale,
    const int* __restrict__ clp, float* __restrict__ outK, u16* __restrict__ Kb)
{
  const int t = blockIdx.x, kh = blockIdx.y, i = threadIdx.x;
  const int cl = *clp;
  const size_t base = (size_t)t * (NKV * HD) + kh * HD;
  const float x1 = kproj[base + i];
  const float x2 = kproj[base + i + 64];
  float ss = x1 * x1 + x2 * x2;
#pragma unroll
  for (int m = 1; m < 64; m <<= 1) ss += __shfl_xor(ss, m, 64);
  const float rstd = rsqrtf(ss * (1.0f / HD) + 1e-6f);
  float y1 = x1 * rstd * kscale[i];
  float y2 = x2 * rstd * kscale[i + 64];
  const int posi = (t < TC) ? ctxpos[t] : npos[t - TC];
  const float ang = (float)posi * exp2f(-(float)i * (19.931568569324174f / 64.0f));
  const float c = cosf(ang), s = sinf(ang);
  const float o1 = y1 * c - y2 * s;
  const float o2 = y2 * c + y1 * s;
  const size_t row = (size_t)cl + t;
  const size_t b0 = ((size_t)(2 * kh) * MAXKV + row) * HD;
  const size_t b1 = ((size_t)(2 * kh + 1) * MAXKV + row) * HD;
  outK[b0 + i] = o1; outK[b0 + i + 64] = o2;
  outK[b1 + i] = o1; outK[b1 + i + 64] = o2;
  if (Kb) {
    const u16 s1 = f2bf(o1), s2 = f2bf(o2);
    Kb[b0 + i] = s1; Kb[b0 + i + 64] = s2;
    Kb[b1 + i] = s1; Kb[b1 + i + 64] = s2;
  }
}

// ============================================================================
// 5) V post: scatter v_proj rows into out cache (GQA repeat)
// ============================================================================
__global__ __launch_bounds__(128) void v_post_k(
    const float* __restrict__ vproj, const int* __restrict__ clp,
    float* __restrict__ outV)
{
  const int t = blockIdx.x, kh = blockIdx.y, h = threadIdx.x;
  const int cl = *clp;
  const float v = vproj[(size_t)t * (NKV * HD) + kh * HD + h];
  const size_t row = (size_t)cl + t;
  outV[((size_t)(2 * kh) * MAXKV + row) * HD + h] = v;
  outV[((size_t)(2 * kh + 1) * MAXKV + row) * HD + h] = v;
}

// ============================================================================
// 6) Flash attention, FIXED-MAX softmax. Scores are Cauchy-Schwarz-bounded:
//    |s| <= sm_scale*log2e*128*max(qs)*max(ks) ~= 18, so exp2(s) <= 2^18 never
//    overflows and the implicit 2^M factor cancels in o/l. No max tracking,
//    no rescale, lane-local l partials reduced once after the loop.
// ============================================================================
__global__ __launch_bounds__(256) void attn_sh(
    const u16* __restrict__ qbf, const u16* __restrict__ Kb,
    const u16* __restrict__ VbT, const int* __restrict__ clp,
    float* __restrict__ Opart, float* __restrict__ Oml, int splits)
{
  __shared__ u16 Ks[2][32 * 128];   // [s][h], rows XOR-swizzled by (row&7)<<4 bytes
  __shared__ u16 Vt[2][128 * 32];   // [h][s], stride 32
  __shared__ u16 Ps[4][16 * 40];    // per-wave P, [t][s], stride 40

  const int tid = threadIdx.x;
  const int lane = tid & 63, wave = tid >> 6;
  const int quad = lane >> 4, m16 = lane & 15;

  const int lin = blockIdx.x;
  const int ppx = (NH * splits) >> 3;         // pairs per XCD
  const int c = lin & 7;
  const int jj = lin >> 3;
  const int pair = c * ppx + (jj % ppx);
  const int x = jj / ppx;
  const int head = pair & (NH - 1);
  const int z = pair >> 4;

  const int qbase = x * 64 + wave * 16;
  const int Svalid = *clp + TNEW;
  const int ntiles = (Svalid + 31) >> 5;
  const int per = (ntiles + splits - 1) / splits;
  const int it0 = z * per;
  const int it1 = (ntiles < it0 + per) ? ntiles : (it0 + per);

  short8 qf[4];
#pragma unroll
  for (int kb = 0; kb < 4; kb++)
    qf[kb] = ldfrag(&qbf[((size_t)(qbase + m16) * NH + head) * HD + kb * 32 + quad * 8]);

  floatx4 O[8];
#pragma unroll
  for (int i = 0; i < 8; i++)
#pragma unroll
    for (int r = 0; r < 4; r++) O[i][r] = 0.0f;
  float lrow[4];
#pragma unroll
  for (int r = 0; r < 4; r++) lrow[r] = 0.0f;

  const int krow = tid >> 4;
  const int ksrccol = ((tid & 15) * 16) ^ ((krow & 7) << 4);
  const char* Kbase = (const char*)(Kb + (size_t)head * MAXKV * HD);
  const int vh = tid >> 2;
  const int vs8 = (tid & 3) * 8;
  const char* Vbase = (const char*)(VbT + (size_t)head * HD * MAXKV);
  u16* myPs = &Ps[wave][0];
  const int kxor = (m16 & 7) << 4;
  const int wb = wave * 512;

  int b = 0;
  if (it0 < it1) {
    {
      const int s0 = it0 * 32;
      gload16(Kbase + ((size_t)(s0 + krow) << 8) + ksrccol,          &Ks[0][wb]);
      gload16(Kbase + ((size_t)(s0 + krow + 16) << 8) + ksrccol,     &Ks[0][2048 + wb]);
      gload16(Vbase + (((size_t)vh * MAXKV + s0 + vs8) << 1),        &Vt[0][wb]);
      gload16(Vbase + (((size_t)(vh + 64) * MAXKV + s0 + vs8) << 1), &Vt[0][2048 + wb]);
    }
    for (int it = it0; it < it1; ++it) {
      if (it + 1 < it1) {
        const int s1 = (it + 1) * 32;
        u16* KsN = &Ks[b ^ 1][0];
        u16* VtN = &Vt[b ^ 1][0];
        gload16(Kbase + ((size_t)(s1 + krow) << 8) + ksrccol,          KsN + wb);
        gload16(Kbase + ((size_t)(s1 + krow + 16) << 8) + ksrccol,     KsN + 2048 + wb);
        gload16(Vbase + (((size_t)vh * MAXKV + s1 + vs8) << 1),        VtN + wb);
        gload16(Vbase + (((size_t)(vh + 64) * MAXKV + s1 + vs8) << 1), VtN + 2048 + wb);
        asm volatile("s_waitcnt vmcnt(4) lgkmcnt(0)" ::: "memory");
      } else {
        asm volatile("s_waitcnt vmcnt(0) lgkmcnt(0)" ::: "memory");
      }
      __builtin_amdgcn_s_barrier();
      __builtin_amdgcn_sched_barrier(0);

      const u16* KsB = &Ks[b][0];
      const u16* VtB = &Vt[b][0];
      const int s0 = it * 32;

      floatx4 sc[2];
#pragma unroll
      for (int st = 0; st < 2; st++) {
        floatx4 a;
#pragma unroll
        for (int r = 0; r < 4; r++) a[r] = 0.0f;
        const int rofs = (st * 16 + m16) * 128;
#pragma unroll
        for (int kb = 0; kb < 4; kb++) {
          short8 kf = ldfrag(&KsB[rofs + (((kb * 64 + quad * 16) ^ kxor) >> 1)]);
          a = __builtin_amdgcn_mfma_f32_16x16x32_bf16(qf[kb], kf, a, 0, 0, 0);
        }
        const int scol = s0 + st * 16 + m16;
        if (scol >= Svalid) {
#pragma unroll
          for (int r = 0; r < 4; r++) a[r] = -1e30f;
        }
        sc[st] = a;
      }

      // fixed-max softmax: p = exp2(s), bounded by 2^18; masked cols -> 0
#pragma unroll
      for (int st = 0; st < 2; st++)
#pragma unroll
        for (int r = 0; r < 4; r++) sc[st][r] = exp2f(sc[st][r]);
#pragma unroll
      for (int r = 0; r < 4; r++) lrow[r] += sc[0][r] + sc[1][r];

#pragma unroll
      for (int st = 0; st < 2; st++)
#pragma unroll
        for (int r = 0; r < 4; r++)
          myPs[(quad * 4 + r) * 40 + st * 16 + m16] = f2bf(sc[st][r]);
      short8 pfr = ldfrag(&myPs[m16 * 40 + quad * 8]);
#pragma unroll
      for (int hb = 0; hb < 8; hb++) {
        short8 vf = ldfrag(&VtB[(hb * 16 + m16) * 32 + quad * 8]);
        O[hb] = __builtin_amdgcn_mfma_f32_16x16x32_bf16(pfr, vf, O[hb], 0, 0, 0);
      }

      asm volatile("s_waitcnt lgkmcnt(0)" ::: "memory");
      __builtin_amdgcn_s_barrier();
      __builtin_amdgcn_sched_barrier(0);
      b ^= 1;
    }
  }

  // reduce l across the 16 lanes of each q-row (once, after the loop)
#pragma unroll
  for (int r = 0; r < 4; r++) {
    lrow[r] += __shfl_xor(lrow[r], 1, 64);
    lrow[r] += __shfl_xor(lrow[r], 2, 64);
    lrow[r] += __shfl_xor(lrow[r], 4, 64);
    lrow[r] += __shfl_xor(lrow[r], 8, 64);
  }

  // write unnormalized partials + (m=0, l)
  const size_t zbase = (size_t)z * TN * NH;
  const int trow = qbase + quad * 4;
#pragma unroll
  for (int hb = 0; hb < 8; hb++)
#pragma unroll
    for (int r = 0; r < 4; r++)
      Opart[(zbase + (size_t)(trow + r) * NH + head) * HD + hb * 16 + m16] = O[hb][r];
  if (m16 == 0) {
#pragma unroll
    for (int r = 0; r < 4; r++) {
      Oml[(zbase + (size_t)(trow + r) * NH + head) * 2 + 0] = 0.0f;
      Oml[(zbase + (size_t)(trow + r) * NH + head) * 2 + 1] = lrow[r];
    }
  }
}

// ============================================================================
// 6-legacy) fallback attention reading f32 caches (used if ws too small)
// ============================================================================
__global__ __launch_bounds__(256) void attn_k(
    const u16* __restrict__ qbf, const float* __restrict__ outK,
    const float* __restrict__ outV, const int* __restrict__ clp,
    float* __restrict__ Opart, float* __restrict__ Oml)
{
  __shared__ u16 Ksl[32 * 136];
  __shared__ u16 Vtl[128 * 40];
  __shared__ u16 Psl[4 * 16 * 40];
  const int tid = threadIdx.x;
  const int lane = tid & 63, wave = tid >> 6;
  const int quad = lane >> 4, m16 = lane & 15;
  const int head = blockIdx.y;
  const int qbase = blockIdx.x * 64 + wave * 16;
  const int z = blockIdx.z, splits = gridDim.z;
  const int Svalid = *clp + TNEW;
  const int ntiles = (Svalid + 31) >> 5;
  const int per = (ntiles + splits - 1) / splits;
  const int it0 = z * per;
  const int it1 = min(ntiles, it0 + per);

  short8 qf[4];
#pragma unroll
  for (int kb = 0; kb < 4; kb++)
    qf[kb] = ldfrag(&qbf[((size_t)(qbase + m16) * NH + head) * HD + kb * 32 + quad * 8]);

  floatx4 O[8];
#pragma unroll
  for (int i = 0; i < 8; i++)
#pragma unroll
    for (int r = 0; r < 4; r++) O[i][r] = 0.0f;
  float mrow[4], lrow[4];
#pragma unroll
  for (int r = 0; r < 4; r++) { mrow[r] = -1e30f; lrow[r] = 0.0f; }

  const int sstage = tid >> 3;
  const int hg = (tid & 7) * 16;

  for (int it = it0; it < it1; it++) {
    const int s0 = it * 32;
    {
      int srow = s0 + sstage; if (srow > MAXKV - 1) srow = MAXKV - 1;
      const float* kp = outK + ((size_t)head * MAXKV + srow) * HD + hg;
      float tv[16];
      *(float4*)(tv)      = *(const float4*)(kp);
      *(float4*)(tv + 4)  = *(const float4*)(kp + 4);
      *(float4*)(tv + 8)  = *(const float4*)(kp + 8);
      *(float4*)(tv + 12) = *(const float4*)(kp + 12);
      *(uint4*)&Ksl[sstage * 136 + hg]     = pack8(tv);
      *(uint4*)&Ksl[sstage * 136 + hg + 8] = pack8(tv + 8);
      const float* vp = outV + ((size_t)head * MAXKV + srow) * HD + hg;
      float vv[16];
      *(float4*)(vv)      = *(const float4*)(vp);
      *(float4*)(vv + 4)  = *(const float4*)(vp + 4);
      *(float4*)(vv + 8)  = *(const float4*)(vp + 8);
      *(float4*)(vv + 12) = *(const float4*)(vp + 12);
#pragma unroll
      for (int j = 0; j < 16; j++) Vtl[(hg + j) * 40 + sstage] = f2bf(vv[j]);
    }
    __syncthreads();

    floatx4 sc[2];
#pragma unroll
    for (int st = 0; st < 2; st++) {
      floatx4 a;
#pragma unroll
      for (int r = 0; r < 4; r++) a[r] = 0.0f;
#pragma unroll
      for (int kb = 0; kb < 4; kb++) {
        short8 kf = ldfrag(&Ksl[(st * 16 + m16) * 136 + kb * 32 + quad * 8]);
        a = __builtin_amdgcn_mfma_f32_16x16x32_bf16(qf[kb], kf, a, 0, 0, 0);
      }
      const int scol = s0 + st * 16 + m16;
      if (scol >= Svalid) {
#pragma unroll
        for (int r = 0; r < 4; r++) a[r] = -1e30f;
      }
      sc[st] = a;
    }

    float alpha[4];
#pragma unroll
    for (int r = 0; r < 4; r++) {
      float mx = fmaxf(sc[0][r], sc[1][r]);
      mx = fmaxf(mx, __shfl_xor(mx, 1, 64));
      mx = fmaxf(mx, __shfl_xor(mx, 2, 64));
      mx = fmaxf(mx, __shfl_xor(mx, 4, 64));
      mx = fmaxf(mx, __shfl_xor(mx, 8, 64));
      const float mn = fmaxf(mrow[r], mx);
      alpha[r] = exp2f(mrow[r] - mn);
      const float p0 = exp2f(sc[0][r] - mn);
      const float p1 = exp2f(sc[1][r] - mn);
      sc[0][r] = p0; sc[1][r] = p1;
      float rs = p0 + p1;
      rs += __shfl_xor(rs, 1, 64);
      rs += __shfl_xor(rs, 2, 64);
      rs += __shfl_xor(rs, 4, 64);
      rs += __shfl_xor(rs, 8, 64);
      lrow[r] = lrow[r] * alpha[r] + rs;
      mrow[r] = mn;
    }
#pragma unroll
    for (int hb = 0; hb < 8; hb++)
#pragma unroll
      for (int r = 0; r < 4; r++) O[hb][r] *= alpha[r];

    u16* myPs = &Psl[wave * 640];
#pragma unroll
    for (int st = 0; st < 2; st++)
#pragma unroll
      for (int r = 0; r < 4; r++)
        myPs[(quad * 4 + r) * 40 + st * 16 + m16] = f2bf(sc[st][r]);
    short8 pf = ldfrag(&myPs[m16 * 40 + quad * 8]);
#pragma unroll
    for (int hb = 0; hb < 8; hb++) {
      short8 vf = ldfrag(&Vtl[(hb * 16 + m16) * 40 + quad * 8]);
      O[hb] = __builtin_amdgcn_mfma_f32_16x16x32_bf16(pf, vf, O[hb], 0, 0, 0);
    }
    __syncthreads();
  }

  const size_t zbase = (size_t)z * TN * NH;
  const int trow = qbase + quad * 4;
#pragma unroll
  for (int hb = 0; hb < 8; hb++)
#pragma unroll
    for (int r = 0; r < 4; r++)
      Opart[(zbase + (size_t)(trow + r) * NH + head) * HD + hb * 16 + m16] = O[hb][r];
  if (m16 == 0) {
#pragma unroll
    for (int r = 0; r < 4; r++) {
      Oml[(zbase + (size_t)(trow + r) * NH + head) * 2 + 0] = mrow[r];
      Oml[(zbase + (size_t)(trow + r) * NH + head) * 2 + 1] = lrow[r];
    }
  }
}

// ============================================================================
// 6b) combine split-S partials -> attnb (f32) and attnbf (bf16)
// ============================================================================
__global__ __launch_bounds__(128) void attn_combine(
    const float* __restrict__ Opart, const float* __restrict__ Oml,
    float* __restrict__ attnb, u16* __restrict__ attnbf, int splits)
{
  const int pair = blockIdx.x;   // t*NH + head
  const int h = threadIdx.x;
  float M = -1e30f;
  for (int zz = 0; zz < splits; zz++)
    M = fmaxf(M, Oml[((size_t)zz * TN * NH + pair) * 2]);
  float l = 0.0f, o = 0.0f;
  for (int zz = 0; zz < splits; zz++) {
    const float mi = Oml[((size_t)zz * TN * NH + pair) * 2];
    const float li = Oml[((size_t)zz * TN * NH + pair) * 2 + 1];
    const float w = exp2f(mi - M);
    l += li * w;
    o += Opart[((size_t)zz * TN * NH + pair) * HD + h] * w;
  }
  const float res = o / l;
  attnb[(size_t)pair * HD + h] = res;
  if (attnbf) attnbf[(size_t)pair * HD + h] = f2bf(res);
}

// ============================================================================
// launch
// ============================================================================
extern "C" void kernel_launch(void* const* d_in, const int* in_sizes, int n_in,
                              void* d_out, int out_size, void* d_ws, size_t ws_size,
                              hipStream_t stream) {
  const float* x_noise       = (const float*)d_in[0];
  const float* target_hidden = (const float*)d_in[1];
  const int*   noise_pos     = (const int*)d_in[2];
  const int*   ctx_pos       = (const int*)d_in[3];
  const float* inK           = (const float*)d_in[4];
  const float* inV           = (const float*)d_in[5];
  const int*   cache_len     = (const int*)d_in[6];
  const float* wq            = (const float*)d_in[7];
  const float* wk            = (const float*)d_in[8];
  const float* wv            = (const float*)d_in[9];
  const float* wo            = (const float*)d_in[10];
  const float* q_scale       = (const float*)d_in[11];
  const float* k_scale       = (const float*)d_in[12];

  float* out0 = (float*)d_out;
  float* outK = out0 + (size_t)TN * HIDDEN;
  float* outV = outK + (size_t)NH * MAXKV * HD;

  // ---- workspace layout ----
  size_t off = 0;
  auto walloc = [&](size_t bytes) -> void* {
    void* p = (char*)d_ws + off;
    off += (bytes + 255) & ~(size_t)255;
    return p;
  };
  u16*   qbf    = (u16*)walloc((size_t)TN * HIDDEN * 2);
  float* attnb  = (float*)walloc((size_t)TN * HIDDEN * 4);
  u16*   attnbf = (u16*)walloc((size_t)TN * HIDDEN * 2);
  float* qproj  = (float*)walloc((size_t)TN * HIDDEN * 4);
  float* kproj  = (float*)walloc((size_t)TNEW * NKV * HD * 4);
  float* vproj  = (float*)walloc((size_t)TNEW * NKV * HD * 4);

  const size_t PER_SPLIT = (size_t)TN * NH * HD * 4 + (size_t)TN * NH * 8;
  const size_t SHB   = (size_t)NH * MAXKV * HD * sizeof(u16);   // 32 MB each
  const size_t GPART = (size_t)4 * TN * HIDDEN * 4;             // 16 MB
  const size_t CONVB = ((size_t)TN * HIDDEN + (size_t)TC * HIDDEN) * 2
                     + ((size_t)HIDDEN * HIDDEN * 2
                      + (size_t)HIDDEN * (NKV * HD) * 2) * 2;
  auto maxsz = [](size_t a, size_t b) { return a > b ? a : b; };

  size_t avail = (ws_size > off) ? ws_size - off : 0;
  bool conv = false;
  int asplits = 0;
  if (avail >= CONVB + 2 * SHB + maxsz(8 * PER_SPLIT, GPART))      { conv = true; asplits = 8; }
  else if (avail >= CONVB + 2 * SHB + maxsz(4 * PER_SPLIT, GPART)) { conv = true; asplits = 4; }
  else if (avail >= 2 * SHB + maxsz(8 * PER_SPLIT, GPART))         { asplits = 8; }
  else if (avail >= 2 * SHB + maxsz(4 * PER_SPLIT, GPART))         { asplits = 4; }
  const bool shadow = (asplits > 0);

  u16 *xbf = nullptr, *thbf = nullptr, *wqT = nullptr, *wkT = nullptr,
      *wvT = nullptr, *woT = nullptr;
  if (conv) {
    xbf  = (u16*)walloc((size_t)TN * HIDDEN * 2);
    thbf = (u16*)walloc((size_t)TC * HIDDEN * 2);
    wqT  = (u16*)walloc((size_t)HIDDEN * HIDDEN * 2);
    wkT  = (u16*)walloc((size_t)HIDDEN * (NKV * HD) * 2);
    wvT  = (u16*)walloc((size_t)HIDDEN * (NKV * HD) * 2);
    woT  = (u16*)walloc((size_t)HIDDEN * HIDDEN * 2);
  }
  u16 *Kb = nullptr, *VbT = nullptr;
  if (shadow) {
    Kb  = (u16*)walloc(SHB);
    VbT = (u16*)walloc(SHB);
  }

  float* scratch = (float*)((char*)d_ws + off);
  const size_t avail2 = (ws_size > off) ? ws_size - off : 0;
  if (!shadow) {
    asplits = 2;
    if (avail2 >= 8 * PER_SPLIT) asplits = 8;
    else if (avail2 >= 4 * PER_SPLIT) asplits = 4;
  }
  float* Opart = scratch;
  float* Oml   = Opart + (size_t)asplits * TN * NH * HD;
  const bool ksplit = (avail2 >= GPART);
  float* gpart = scratch;   // shared with Opart (phases don't overlap)

  if (conv) {
    conv_bf16<<<dim3((TN * HIDDEN / 4 + 255) / 256), dim3(256), 0, stream>>>(
        (const float4*)x_noise, (uint2*)xbf, TN * HIDDEN / 4);
    conv_bf16<<<dim3((TC * HIDDEN / 4 + 255) / 256), dim3(256), 0, stream>>>(
        (const float4*)target_hidden, (uint2*)thbf, TC * HIDDEN / 4);
    transpose_bf16<<<dim3(HIDDEN / 64, HIDDEN / 64), dim3(256), 0, stream>>>(
        wq, wqT, HIDDEN, HIDDEN);
    transpose_bf16<<<dim3(NKV * HD / 64, HIDDEN / 64), dim3(256), 0, stream>>>(
        wk, wkT, HIDDEN, NKV * HD);
    transpose_bf16<<<dim3(NKV * HD / 64, HIDDEN / 64), dim3(256), 0, stream>>>(
        wv, wvT, HIDDEN, NKV * HD);
    transpose_bf16<<<dim3(HIDDEN / 64, HIDDEN / 64), dim3(256), 0, stream>>>(
        wo, woT, NH * HD, HIDDEN);
  }

  cache_copy<<<dim3(32768), dim3(256), 0, stream>>>(
      (const float4*)inK, (const float4*)inV, (float4*)outK, (float4*)outV,
      cache_len, Kb);

  // Q projection
  if (conv && ksplit) {
    gemm_v2<<<dim3(HIDDEN / 128, TN / 128, 4), dim3(256), 0, stream>>>(
        xbf, TN, xbf, wqT, wqT, HIDDEN, gpart, gpart, TN, HIDDEN, HIDDEN, 16);
    reduce4<<<dim3((TN * HIDDEN / 4 + 255) / 256), dim3(256), 0, stream>>>(
        (const float4*)gpart, (float4*)qproj, TN * HIDDEN / 4);
  } else if (conv) {
    gemm_v2<<<dim3(HIDDEN / 128, TN / 128, 1), dim3(256), 0, stream>>>(
        xbf, TN, xbf, wqT, wqT, HIDDEN, qproj, qproj, TN, HIDDEN, HIDDEN, 64);
  } else if (ksplit) {
    gemm_bf16<<<dim3(HIDDEN / 64, TN / 64, 4), dim3(256), 0, stream>>>(
        x_noise, TN, x_noise, wq, wq, HIDDEN, gpart, gpart, TN, HIDDEN, HIDDEN, 16);
    reduce4<<<dim3((TN * HIDDEN / 4 + 255) / 256), dim3(256), 0, stream>>>(
        (const float4*)gpart, (float4*)qproj, TN * HIDDEN / 4);
  } else {
    gemm_bf16<<<dim3(HIDDEN / 64, TN / 64, 1), dim3(256), 0, stream>>>(
        x_noise, TN, x_noise, wq, wq, HIDDEN, qproj, qproj, TN, HIDDEN, HIDDEN, 64);
  }

  // merged K+V projection
  if (conv) {
    gemm_v2<<<dim3(2 * NKV * HD / 128, TNEW / 128, 1), dim3(256), 0, stream>>>(
        thbf, TC, xbf, wkT, wvT, NKV * HD, kproj, vproj,
        TNEW, 2 * NKV * HD, HIDDEN, 64);
  } else {
    gemm_bf16<<<dim3(2 * NKV * HD / 64, TNEW / 64, 1), dim3(256), 0, stream>>>(
        target_hidden, TC, x_noise, wk, wv, NKV * HD, kproj, vproj,
        TNEW, 2 * NKV * HD, HIDDEN, 64);
  }

  q_post_k<<<dim3(TN, NH), dim3(64), 0, stream>>>(qproj, noise_pos, q_scale, qbf);
  k_post_k<<<dim3(TNEW, NKV), dim3(64), 0, stream>>>(
      kproj, ctx_pos, noise_pos, k_scale, cache_len, outK, Kb);
  v_post_k<<<dim3(TNEW, NKV), dim3(128), 0, stream>>>(vproj, cache_len, outV);
  if (shadow) {
    vT_build<<<dim3(MAXKV / 64, HD / 64, NH), dim3(256), 0, stream>>>(
        inV, vproj, cache_len, VbT);
  }

  if (shadow) {
    attn_sh<<<dim3((TN / 64) * NH * asplits), dim3(256), 0, stream>>>(
        qbf, Kb, VbT, cache_len, Opart, Oml, asplits);
  } else {
    attn_k<<<dim3(TN / 64, NH, asplits), dim3(256), 0, stream>>>(
        qbf, outK, outV, cache_len, Opart, Oml);
  }
  attn_combine<<<dim3(TN * NH), dim3(128), 0, stream>>>(
      Opart, Oml, attnb, conv ? attnbf : nullptr, asplits);

  // output projection
  if (conv && ksplit) {
    gemm_v2<<<dim3(HIDDEN / 128, TN / 128, 4), dim3(256), 0, stream>>>(
        attnbf, TN, attnbf, woT, woT, HIDDEN, gpart, gpart, TN, HIDDEN, HIDDEN, 16);
    reduce4<<<dim3((TN * HIDDEN / 4 + 255) / 256), dim3(256), 0, stream>>>(
        (const float4*)gpart, (float4*)out0, TN * HIDDEN / 4);
  } else if (conv) {
    gemm_v2<<<dim3(HIDDEN / 128, TN / 128, 1), dim3(256), 0, stream>>>(
        attnbf, TN, attnbf, woT, woT, HIDDEN, out0, out0, TN, HIDDEN, HIDDEN, 64);
  } else if (ksplit) {
    gemm_bf16<<<dim3(HIDDEN / 64, TN / 64, 4), dim3(256), 0, stream>>>(
        attnb, TN, attnb, wo, wo, HIDDEN, gpart, gpart, TN, HIDDEN, HIDDEN, 16);
    reduce4<<<dim3((TN * HIDDEN / 4 + 255) / 256), dim3(256), 0, stream>>>(
        (const float4*)gpart, (float4*)out0, TN * HIDDEN / 4);
  } else {
    gemm_bf16<<<dim3(HIDDEN / 64, TN / 64, 1), dim3(256), 0, stream>>>(
        attnb, TN, attnb, wo, wo, HIDDEN, out0, out0, TN, HIDDEN, HIDDEN, 64);
  }
}

// Round 5
// 459.387 us; speedup vs baseline: 1.2311x; 1.0223x over previous
//
#include <hip/hip_runtime.h>
#include <hip/hip_bf16.h>

// ---- problem constants ----
#define HIDDEN 2048
#define NH 16
#define NKV 8
#define HD 128
#define TN 512      // T_NOISE
#define TC 1536     // T_CTX
#define TNEW 2048   // TC + TN
#define MAXKV 8192

using u16 = unsigned short;
using u32 = unsigned int;

typedef short short8 __attribute__((ext_vector_type(8)));
typedef float floatx4 __attribute__((ext_vector_type(4)));

__device__ __forceinline__ u16 f2bf(float f) {
  u32 u = __float_as_uint(f);
  u += 0x7FFFu + ((u >> 16) & 1u);   // round-to-nearest-even
  return (u16)(u >> 16);
}

__device__ __forceinline__ uint4 pack8(const float* f) {
  uint4 r;
  r.x = (u32)f2bf(f[0]) | ((u32)f2bf(f[1]) << 16);
  r.y = (u32)f2bf(f[2]) | ((u32)f2bf(f[3]) << 16);
  r.z = (u32)f2bf(f[4]) | ((u32)f2bf(f[5]) << 16);
  r.w = (u32)f2bf(f[6]) | ((u32)f2bf(f[7]) << 16);
  return r;
}

__device__ __forceinline__ short8 ldfrag(const u16* p) {
  uint4 v = *(const uint4*)p;
  return __builtin_bit_cast(short8, v);
}

// async global->LDS, 16B per lane.
// l MUST be wave-uniform: HW writes lane i's 16B at l + i*16.
__device__ __forceinline__ void gload16(const void* g, void* l) {
  __builtin_amdgcn_global_load_lds(
      (const __attribute__((address_space(1))) u32*)g,
      (__attribute__((address_space(3))) u32*)l, 16, 0, 0);
}

// ============================================================================
// 0a) f32 -> bf16 convert (vectorized)
// ============================================================================
__global__ __launch_bounds__(256) void conv_bf16(
    const float4* __restrict__ in, uint2* __restrict__ out, int n4)
{
  int idx = blockIdx.x * 256 + threadIdx.x;
  if (idx >= n4) return;
  float4 v = in[idx];
  uint2 r;
  r.x = (u32)f2bf(v.x) | ((u32)f2bf(v.y) << 16);
  r.y = (u32)f2bf(v.z) | ((u32)f2bf(v.w) << 16);
  out[idx] = r;
}

// ============================================================================
// 0b) f32 [K][N] -> bf16 [N][K] transpose (LDS-tiled 64x64)
// ============================================================================
__global__ __launch_bounds__(256) void transpose_bf16(
    const float* __restrict__ w, u16* __restrict__ wT, int K, int N)
{
  __shared__ float t[64][65];
  const int bk = blockIdx.y * 64, bn = blockIdx.x * 64;
  const int tid = threadIdx.x;
  const int r = tid >> 4, c4 = (tid & 15) * 4;
#pragma unroll
  for (int rr = 0; rr < 4; rr++) {
    float4 v = *(const float4*)(w + (size_t)(bk + rr * 16 + r) * N + bn + c4);
    t[rr * 16 + r][c4 + 0] = v.x;
    t[rr * 16 + r][c4 + 1] = v.y;
    t[rr * 16 + r][c4 + 2] = v.z;
    t[rr * 16 + r][c4 + 3] = v.w;
  }
  __syncthreads();
  const int n = tid >> 2, k16 = (tid & 3) * 16;
  u32 wbuf[8];
#pragma unroll
  for (int jj = 0; jj < 8; jj++) {
    float lo = t[k16 + 2 * jj][n], hi = t[k16 + 2 * jj + 1][n];
    wbuf[jj] = (u32)f2bf(lo) | ((u32)f2bf(hi) << 16);
  }
  *(uint4*)(&wT[(size_t)(bn + n) * K + bk + k16])     = *(uint4*)(wbuf);
  *(uint4*)(&wT[(size_t)(bn + n) * K + bk + k16 + 8]) = *(uint4*)(wbuf + 4);
}

// ============================================================================
// 0c) Build VbT[head][h][s] bf16 from inV (s < cl) / vproj (cl <= s < cl+TNEW)
// ============================================================================
__global__ __launch_bounds__(256) void vT_build(
    const float* __restrict__ inV, const float* __restrict__ vproj,
    const int* __restrict__ clp, u16* __restrict__ VbT)
{
  __shared__ float t[64][65];
  const int cl = *clp;
  const int s0 = blockIdx.x * 64;
  const int slim = cl + TNEW;
  if (s0 >= slim) return;                  // rows never read by attention
  const int h0 = blockIdx.y * 64;
  const int head = blockIdx.z;
  const int tid = threadIdx.x;

  const int rr = tid >> 2, c16 = (tid & 3) * 16;
  int s = s0 + rr;
  if (s >= slim) s = slim - 1;             // clamp (dup row, unread)
  const float* src = (s < cl)
      ? inV + ((size_t)head * MAXKV + s) * HD + (h0 + c16)
      : vproj + (size_t)(s - cl) * (NKV * HD) + (head >> 1) * HD + (h0 + c16);
  float4 v0 = ((const float4*)src)[0];
  float4 v1 = ((const float4*)src)[1];
  float4 v2 = ((const float4*)src)[2];
  float4 v3 = ((const float4*)src)[3];
  *(float4*)&t[rr][c16 + 0]  = v0;
  *(float4*)&t[rr][c16 + 4]  = v1;
  *(float4*)&t[rr][c16 + 8]  = v2;
  *(float4*)&t[rr][c16 + 12] = v3;
  __syncthreads();

  const int hh = tid >> 2, sseg = (tid & 3) * 16;
  u32 wbuf[8];
#pragma unroll
  for (int j = 0; j < 8; j++)
    wbuf[j] = (u32)f2bf(t[sseg + 2 * j][hh]) | ((u32)f2bf(t[sseg + 2 * j + 1][hh]) << 16);
  u16* dst = VbT + ((size_t)head * HD + h0 + hh) * MAXKV + s0 + sseg;
  *(uint4*)(dst)     = *(uint4*)(wbuf);
  *(uint4*)(dst + 8) = *(uint4*)(wbuf + 4);
}

// ============================================================================
// 1) Copy kv caches to output, skipping the scatter window. Also emits bf16
//    K shadow Kb[head][s][h] (coalesced). V shadow handled by vT_build.
// ============================================================================
__global__ __launch_bounds__(256) void cache_copy(
    const float4* __restrict__ inK, const float4* __restrict__ inV,
    float4* __restrict__ outK, float4* __restrict__ outV,
    const int* __restrict__ clp, u16* __restrict__ Kb)
{
  const int cl = *clp;
  long long idx = (long long)blockIdx.x * 256 + threadIdx.x;
  const long long per = (long long)NH * MAXKV * (HD / 4);   // 4,194,304
  const float4* src; float4* dst; bool isv;
  long long r = idx;
  if (r < per) { src = inK; dst = outK; isv = false; }
  else { r -= per; src = inV; dst = outV; isv = true; }
  int row = (int)((r >> 5) & (MAXKV - 1));  // s index within a head
  if (row >= cl && row < cl + TNEW) return; // will be written by scatter
  float4 v = src[r];
  dst[r] = v;
  if (!isv && row < cl && Kb) {
    uint2 p;
    p.x = (u32)f2bf(v.x) | ((u32)f2bf(v.y) << 16);
    p.y = (u32)f2bf(v.z) | ((u32)f2bf(v.w) << 16);
    *(uint2*)(Kb + (size_t)r * 4) = p;
  }
}

// ============================================================================
// 2) GEMM: bf16 A [M][K], bf16 B^T [N][K], f32 C. 64x128 tile (BM=64, BN=128),
//    BK=32, 4 waves (2x2, wave tile 32x64). 2x the blocks of 128x128 -> 2
//    blocks/CU (was 1 = no TLP). LDS rows are 64 B: XOR-swizzle bank fix
//    (((row>>1)&3)<<4 bytes) applied to BOTH staged source col and ds_read.
// ============================================================================
__global__ __launch_bounds__(256) void gemm_v2(
    const u16* __restrict__ A0, int rows0, const u16* __restrict__ A1,
    const u16* __restrict__ B0, const u16* __restrict__ B1, int Nhalf,
    float* __restrict__ C0, float* __restrict__ C1,
    int M, int N, int K, int ksteps)
{
  __shared__ u16 As[2][64 * 32];    // 4 KB / buf
  __shared__ u16 Bs[2][128 * 32];   // 8 KB / buf
  const int tid = threadIdx.x;
  const int lane = tid & 63, wave = tid >> 6;
  const int quad = lane >> 4, m16 = lane & 15;

  // XCD sub-grid swizzle: each XCD owns a (gx/4)x(gy/2) rectangle of tiles
  const int gx = gridDim.x, gy = gridDim.y;
  int bx = blockIdx.x, by = blockIdx.y;
  if (((gx & 3) == 0) && ((gy & 1) == 0)) {
    const int lin = bx + gx * by;
    const int c = lin & 7, j = lin >> 3;
    const int sw = gx >> 2, sh = gy >> 1;
    bx = (c & 3) * sw + j % sw;
    by = (c >> 2) * sh + j / sw;
  }
  const int bm = by * 64, bn = bx * 128;
  const int wm = (wave >> 1) * 32, wn = (wave & 1) * 64;
  const int z = blockIdx.z;
  const int kbase = z * ksteps * 32;

  const u16* B = (bn < Nhalf) ? B0 : B1;
  float*     C = (bn < Nhalf) ? C0 : C1;
  const int n0 = (bn < Nhalf) ? bn : bn - Nhalf;
  const int strideN = (bn < Nhalf) ? Nhalf : (N - Nhalf);

  floatx4 acc[2][4];
#pragma unroll
  for (int i = 0; i < 2; i++)
#pragma unroll
    for (int j = 0; j < 4; j++)
#pragma unroll
      for (int r = 0; r < 4; r++) acc[i][j][r] = 0.0f;

  // staging: thread t -> row t>>2, dest col (t&3)*16 B; source col pre-swizzled
  const int srow = tid >> 2;                                  // 0..63
  const int sk = ((tid & 3) * 8) ^ (((srow >> 1) & 3) << 3);  // u16 units
  const int ar = bm + srow;
  const u16* Arow = (ar < rows0) ? (A0 + (size_t)ar * K)
                                 : (A1 + (size_t)(ar - rows0) * K);
  const u16* Brow0 = B + (size_t)(n0 + srow) * K;
  const u16* Brow1 = B + (size_t)(n0 + srow + 64) * K;
  const int wb = wave * 512;                                  // 1 KB per wave

  {
    const int k0 = kbase;
    gload16(Arow  + k0 + sk, &As[0][wb]);
    gload16(Brow0 + k0 + sk, &Bs[0][wb]);
    gload16(Brow1 + k0 + sk, &Bs[0][2048 + wb]);
  }
  const int rq = (quad * 8) ^ (((m16 >> 1) & 3) << 3);        // swizzled read col
  int b = 0;
  for (int ks = 0; ks < ksteps; ks++) {
    if (ks + 1 < ksteps) {
      const int k1 = kbase + (ks + 1) * 32;
      gload16(Arow  + k1 + sk, &As[b ^ 1][wb]);
      gload16(Brow0 + k1 + sk, &Bs[b ^ 1][wb]);
      gload16(Brow1 + k1 + sk, &Bs[b ^ 1][2048 + wb]);
      asm volatile("s_waitcnt vmcnt(3)" ::: "memory");  // current tile only
    } else {
      asm volatile("s_waitcnt vmcnt(0)" ::: "memory");
    }
    __builtin_amdgcn_s_barrier();
    __builtin_amdgcn_sched_barrier(0);

    short8 af[2], bfr[4];
#pragma unroll
    for (int i = 0; i < 2; i++)
      af[i] = ldfrag(&As[b][(wm + i * 16 + m16) * 32 + rq]);
#pragma unroll
    for (int j = 0; j < 4; j++)
      bfr[j] = ldfrag(&Bs[b][(wn + j * 16 + m16) * 32 + rq]);
#pragma unroll
    for (int i = 0; i < 2; i++)
#pragma unroll
      for (int j = 0; j < 4; j++)
        acc[i][j] = __builtin_amdgcn_mfma_f32_16x16x32_bf16(af[i], bfr[j], acc[i][j], 0, 0, 0);

    asm volatile("s_waitcnt lgkmcnt(0)" ::: "memory");
    __builtin_amdgcn_s_barrier();
    __builtin_amdgcn_sched_barrier(0);
    b ^= 1;
  }

  const size_t zoff = (size_t)z * M * Nhalf;
#pragma unroll
  for (int i = 0; i < 2; i++)
#pragma unroll
    for (int j = 0; j < 4; j++)
#pragma unroll
      for (int r = 0; r < 4; r++) {
        int row = bm + wm + i * 16 + quad * 4 + r;
        int col = wn + j * 16 + m16;
        C[zoff + (size_t)row * strideN + n0 + col] = acc[i][j][r];
      }
}

// ============================================================================
// 2-legacy) f32-input GEMM (fallback when workspace too small for converts)
// ============================================================================
__global__ __launch_bounds__(256) void gemm_bf16(
    const float* __restrict__ A0, int rows0, const float* __restrict__ A1,
    const float* __restrict__ B0, const float* __restrict__ B1, int Nhalf,
    float* __restrict__ C0, float* __restrict__ C1,
    int M, int N, int K, int ksteps)
{
  __shared__ u16 As[64 * 40];
  __shared__ u16 Bs[64 * 40];
  const int tid = threadIdx.x;
  const int lane = tid & 63;
  const int wave = tid >> 6;
  const int quad = lane >> 4;
  const int m16 = lane & 15;
  const int bm = blockIdx.y * 64;
  const int bn = blockIdx.x * 64;
  const int wm = (wave >> 1) * 32;
  const int wn = (wave & 1) * 32;
  const int z = blockIdx.z;
  const int kbase = z * ksteps * 32;

  const float* B = (bn < Nhalf) ? B0 : B1;
  float*       C = (bn < Nhalf) ? C0 : C1;
  const int n0 = (bn < Nhalf) ? bn : bn - Nhalf;
  const int strideN = (bn < Nhalf) ? Nhalf : (N - Nhalf);

  floatx4 acc[2][2];
#pragma unroll
  for (int i = 0; i < 2; i++)
#pragma unroll
    for (int j = 0; j < 2; j++)
#pragma unroll
      for (int r = 0; r < 4; r++) acc[i][j][r] = 0.0f;

  const int arow = tid >> 2, akg = (tid & 3) * 8;
  const int brow = tid >> 3, bng = (tid & 7) * 8;
  const int garow = bm + arow;
  const float* Ap = (garow < rows0) ? (A0 + (size_t)garow * K)
                                    : (A1 + (size_t)(garow - rows0) * K);

  for (int ks = 0; ks < ksteps; ks++) {
    const int k0 = kbase + ks * 32;
    if (k0 >= K) break;
    float av[8];
    *(float4*)(av)     = *(const float4*)(Ap + k0 + akg);
    *(float4*)(av + 4) = *(const float4*)(Ap + k0 + akg + 4);
    *(uint4*)&As[arow * 40 + akg] = pack8(av);

    float bv[8];
    const float* Bp = B + (size_t)(k0 + brow) * strideN + n0 + bng;
    *(float4*)(bv)     = *(const float4*)(Bp);
    *(float4*)(bv + 4) = *(const float4*)(Bp + 4);
#pragma unroll
    for (int j = 0; j < 8; j++) Bs[(bng + j) * 40 + brow] = f2bf(bv[j]);

    __syncthreads();

    short8 a0 = ldfrag(&As[(wm + m16) * 40 + quad * 8]);
    short8 a1 = ldfrag(&As[(wm + 16 + m16) * 40 + quad * 8]);
    short8 b0 = ldfrag(&Bs[(wn + m16) * 40 + quad * 8]);
    short8 b1 = ldfrag(&Bs[(wn + 16 + m16) * 40 + quad * 8]);
    acc[0][0] = __builtin_amdgcn_mfma_f32_16x16x32_bf16(a0, b0, acc[0][0], 0, 0, 0);
    acc[0][1] = __builtin_amdgcn_mfma_f32_16x16x32_bf16(a0, b1, acc[0][1], 0, 0, 0);
    acc[1][0] = __builtin_amdgcn_mfma_f32_16x16x32_bf16(a1, b0, acc[1][0], 0, 0, 0);
    acc[1][1] = __builtin_amdgcn_mfma_f32_16x16x32_bf16(a1, b1, acc[1][1], 0, 0, 0);

    __syncthreads();
  }

  const size_t zoff = (size_t)z * M * Nhalf;
#pragma unroll
  for (int mt = 0; mt < 2; mt++)
#pragma unroll
    for (int nt = 0; nt < 2; nt++)
#pragma unroll
      for (int r = 0; r < 4; r++) {
        int row = bm + wm + mt * 16 + quad * 4 + r;
        int col = wn + nt * 16 + m16;
        C[zoff + (size_t)row * strideN + n0 + col] = acc[mt][nt][r];
      }
}

// ============================================================================
// 2b) reduce 4 split-K partials: C = sum_z P[z]
// ============================================================================
__global__ __launch_bounds__(256) void reduce4(
    const float4* __restrict__ P, float4* __restrict__ C, int n4)
{
  int idx = blockIdx.x * 256 + threadIdx.x;
  if (idx >= n4) return;
  float4 a = P[idx], b = P[idx + n4], c = P[idx + 2 * n4], d = P[idx + 3 * n4];
  float4 r;
  r.x = (a.x + b.x) + (c.x + d.x);
  r.y = (a.y + b.y) + (c.y + d.y);
  r.z = (a.z + b.z) + (c.z + d.z);
  r.w = (a.w + b.w) + (c.w + d.w);
  C[idx] = r;
}

// ============================================================================
// 3) Q post: RMSNorm(q_scale) + RoPE + fold sm_scale*log2e, emit bf16
// ============================================================================
__global__ __launch_bounds__(64) void q_post_k(
    const float* __restrict__ qproj, const int* __restrict__ npos,
    const float* __restrict__ qscale, u16* __restrict__ qbf)
{
  const int t = blockIdx.x, n = blockIdx.y, i = threadIdx.x;
  const size_t base = (size_t)t * HIDDEN + n * HD;
  const float x1 = qproj[base + i];
  const float x2 = qproj[base + i + 64];
  float ss = x1 * x1 + x2 * x2;
#pragma unroll
  for (int m = 1; m < 64; m <<= 1) ss += __shfl_xor(ss, m, 64);
  const float rstd = rsqrtf(ss * (1.0f / HD) + 1e-6f);
  float y1 = x1 * rstd * qscale[i];
  float y2 = x2 * rstd * qscale[i + 64];
  const float pos = (float)npos[t];
  const float ang = pos * exp2f(-(float)i * (19.931568569324174f / 64.0f));
  const float c = cosf(ang), s = sinf(ang);
  const float sc = 0.08838834764831845f * 1.4426950408889634f;  // sm_scale*log2e
  qbf[base + i]      = f2bf((y1 * c - y2 * s) * sc);
  qbf[base + i + 64] = f2bf((y2 * c + y1 * s) * sc);
}

// ============================================================================
// 4) K post: RMSNorm(k_scale) + RoPE, scatter f32 into out cache (GQA repeat)
//    + bf16 shadow Kb[head][s][h]
// ============================================================================
__global__ __launch_bounds__(64) void k_post_k(
    const float* __restrict__ kproj, const int* __restrict__ ctxpos,
    const int* __restrict__ npos, const float* __restrict__ kscale,
    const int* __restrict__ clp, float* __restrict__ outK, u16* __restrict__ Kb)
{
  const int t = blockIdx.x, kh = blockIdx.y, i = threadIdx.x;
  const int cl = *clp;
  const size_t base = (size_t)t * (NKV * HD) + kh * HD;
  const float x1 = kproj[base + i];
  const float x2 = kproj[base + i + 64];
  float ss = x1 * x1 + x2 * x2;
#pragma unroll
  for (int m = 1; m < 64; m <<= 1) ss += __shfl_xor(ss, m, 64);
  const float rstd = rsqrtf(ss * (1.0f / HD) + 1e-6f);
  float y1 = x1 * rstd * kscale[i];
  float y2 = x2 * rstd * kscale[i + 64];
  const int posi = (t < TC) ? ctxpos[t] : npos[t - TC];
  const float ang = (float)posi * exp2f(-(float)i * (19.931568569324174f / 64.0f));
  const float c = cosf(ang), s = sinf(ang);
  const float o1 = y1 * c - y2 * s;
  const float o2 = y2 * c + y1 * s;
  const size_t row = (size_t)cl + t;
  const size_t b0 = ((size_t)(2 * kh) * MAXKV + row) * HD;
  const size_t b1 = ((size_t)(2 * kh + 1) * MAXKV + row) * HD;
  outK[b0 + i] = o1; outK[b0 + i + 64] = o2;
  outK[b1 + i] = o1; outK[b1 + i + 64] = o2;
  if (Kb) {
    const u16 s1 = f2bf(o1), s2 = f2bf(o2);
    Kb[b0 + i] = s1; Kb[b0 + i + 64] = s2;
    Kb[b1 + i] = s1; Kb[b1 + i + 64] = s2;
  }
}

// ============================================================================
// 5) V post: scatter v_proj rows into out cache (GQA repeat)
// ============================================================================
__global__ __launch_bounds__(128) void v_post_k(
    const float* __restrict__ vproj, const int* __restrict__ clp,
    float* __restrict__ outV)
{
  const int t = blockIdx.x, kh = blockIdx.y, h = threadIdx.x;
  const int cl = *clp;
  const float v = vproj[(size_t)t * (NKV * HD) + kh * HD + h];
  const size_t row = (size_t)cl + t;
  outV[((size_t)(2 * kh) * MAXKV + row) * HD + h] = v;
  outV[((size_t)(2 * kh + 1) * MAXKV + row) * HD + h] = v;
}

// ============================================================================
// 6) Flash attention, fixed-max softmax. Now with V bank swizzle: Vt rows are
//    64 B -> XOR ((row>>1)&3)<<4 bytes on staged source col AND ds_read col
//    (kills the remaining ~4.5e6 bank conflicts/dispatch).
// ============================================================================
__global__ __launch_bounds__(256) void attn_sh(
    const u16* __restrict__ qbf, const u16* __restrict__ Kb,
    const u16* __restrict__ VbT, const int* __restrict__ clp,
    float* __restrict__ Opart, float* __restrict__ Oml, int splits)
{
  __shared__ u16 Ks[2][32 * 128];   // [s][h], rows XOR-swizzled by (row&7)<<4 bytes
  __shared__ u16 Vt[2][128 * 32];   // [h][s], rows XOR-swizzled by ((row>>1)&3)<<4 bytes
  __shared__ u16 Ps[4][16 * 40];    // per-wave P, [t][s], stride 40

  const int tid = threadIdx.x;
  const int lane = tid & 63, wave = tid >> 6;
  const int quad = lane >> 4, m16 = lane & 15;

  const int lin = blockIdx.x;
  const int ppx = (NH * splits) >> 3;         // pairs per XCD
  const int c = lin & 7;
  const int jj = lin >> 3;
  const int pair = c * ppx + (jj % ppx);
  const int x = jj / ppx;
  const int head = pair & (NH - 1);
  const int z = pair >> 4;

  const int qbase = x * 64 + wave * 16;
  const int Svalid = *clp + TNEW;
  const int ntiles = (Svalid + 31) >> 5;
  const int per = (ntiles + splits - 1) / splits;
  const int it0 = z * per;
  const int it1 = (ntiles < it0 + per) ? ntiles : (it0 + per);

  short8 qf[4];
#pragma unroll
  for (int kb = 0; kb < 4; kb++)
    qf[kb] = ldfrag(&qbf[((size_t)(qbase + m16) * NH + head) * HD + kb * 32 + quad * 8]);

  floatx4 O[8];
#pragma unroll
  for (int i = 0; i < 8; i++)
#pragma unroll
    for (int r = 0; r < 4; r++) O[i][r] = 0.0f;
  float lrow[4];
#pragma unroll
  for (int r = 0; r < 4; r++) lrow[r] = 0.0f;

  const int krow = tid >> 4;
  const int ksrccol = ((tid & 15) * 16) ^ ((krow & 7) << 4);
  const char* Kbase = (const char*)(Kb + (size_t)head * MAXKV * HD);
  const int vh = tid >> 2;
  const int vs8 = ((tid & 3) * 8) ^ (((vh >> 1) & 3) << 3);   // pre-swizzled src col (u16)
  const char* Vbase = (const char*)(VbT + (size_t)head * HD * MAXKV);
  u16* myPs = &Ps[wave][0];
  const int kxor = (m16 & 7) << 4;
  const int vq = (quad * 8) ^ (((m16 >> 1) & 3) << 3);        // swizzled Vt read col (u16)
  const int wb = wave * 512;

  int b = 0;
  if (it0 < it1) {
    {
      const int s0 = it0 * 32;
      gload16(Kbase + ((size_t)(s0 + krow) << 8) + ksrccol,          &Ks[0][wb]);
      gload16(Kbase + ((size_t)(s0 + krow + 16) << 8) + ksrccol,     &Ks[0][2048 + wb]);
      gload16(Vbase + (((size_t)vh * MAXKV + s0 + vs8) << 1),        &Vt[0][wb]);
      gload16(Vbase + (((size_t)(vh + 64) * MAXKV + s0 + vs8) << 1), &Vt[0][2048 + wb]);
    }
    for (int it = it0; it < it1; ++it) {
      if (it + 1 < it1) {
        const int s1 = (it + 1) * 32;
        u16* KsN = &Ks[b ^ 1][0];
        u16* VtN = &Vt[b ^ 1][0];
        gload16(Kbase + ((size_t)(s1 + krow) << 8) + ksrccol,          KsN + wb);
        gload16(Kbase + ((size_t)(s1 + krow + 16) << 8) + ksrccol,     KsN + 2048 + wb);
        gload16(Vbase + (((size_t)vh * MAXKV + s1 + vs8) << 1),        VtN + wb);
        gload16(Vbase + (((size_t)(vh + 64) * MAXKV + s1 + vs8) << 1), VtN + 2048 + wb);
        asm volatile("s_waitcnt vmcnt(4) lgkmcnt(0)" ::: "memory");
      } else {
        asm volatile("s_waitcnt vmcnt(0) lgkmcnt(0)" ::: "memory");
      }
      __builtin_amdgcn_s_barrier();
      __builtin_amdgcn_sched_barrier(0);

      const u16* KsB = &Ks[b][0];
      const u16* VtB = &Vt[b][0];
      const int s0 = it * 32;

      floatx4 sc[2];
#pragma unroll
      for (int st = 0; st < 2; st++) {
        floatx4 a;
#pragma unroll
        for (int r = 0; r < 4; r++) a[r] = 0.0f;
        const int rofs = (st * 16 + m16) * 128;
#pragma unroll
        for (int kb = 0; kb < 4; kb++) {
          short8 kf = ldfrag(&KsB[rofs + (((kb * 64 + quad * 16) ^ kxor) >> 1)]);
          a = __builtin_amdgcn_mfma_f32_16x16x32_bf16(qf[kb], kf, a, 0, 0, 0);
        }
        const int scol = s0 + st * 16 + m16;
        if (scol >= Svalid) {
#pragma unroll
          for (int r = 0; r < 4; r++) a[r] = -1e30f;
        }
        sc[st] = a;
      }

      // fixed-max softmax: p = exp2(s), bounded by 2^18; masked cols -> 0
#pragma unroll
      for (int st = 0; st < 2; st++)
#pragma unroll
        for (int r = 0; r < 4; r++) sc[st][r] = exp2f(sc[st][r]);
#pragma unroll
      for (int r = 0; r < 4; r++) lrow[r] += sc[0][r] + sc[1][r];

#pragma unroll
      for (int st = 0; st < 2; st++)
#pragma unroll
        for (int r = 0; r < 4; r++)
          myPs[(quad * 4 + r) * 40 + st * 16 + m16] = f2bf(sc[st][r]);
      short8 pfr = ldfrag(&myPs[m16 * 40 + quad * 8]);
#pragma unroll
      for (int hb = 0; hb < 8; hb++) {
        short8 vf = ldfrag(&VtB[(hb * 16 + m16) * 32 + vq]);
        O[hb] = __builtin_amdgcn_mfma_f32_16x16x32_bf16(pfr, vf, O[hb], 0, 0, 0);
      }

      asm volatile("s_waitcnt lgkmcnt(0)" ::: "memory");
      __builtin_amdgcn_s_barrier();
      __builtin_amdgcn_sched_barrier(0);
      b ^= 1;
    }
  }

  // reduce l across the 16 lanes of each q-row (once, after the loop)
#pragma unroll
  for (int r = 0; r < 4; r++) {
    lrow[r] += __shfl_xor(lrow[r], 1, 64);
    lrow[r] += __shfl_xor(lrow[r], 2, 64);
    lrow[r] += __shfl_xor(lrow[r], 4, 64);
    lrow[r] += __shfl_xor(lrow[r], 8, 64);
  }

  // write unnormalized partials + (m=0, l)
  const size_t zbase = (size_t)z * TN * NH;
  const int trow = qbase + quad * 4;
#pragma unroll
  for (int hb = 0; hb < 8; hb++)
#pragma unroll
    for (int r = 0; r < 4; r++)
      Opart[(zbase + (size_t)(trow + r) * NH + head) * HD + hb * 16 + m16] = O[hb][r];
  if (m16 == 0) {
#pragma unroll
    for (int r = 0; r < 4; r++) {
      Oml[(zbase + (size_t)(trow + r) * NH + head) * 2 + 0] = 0.0f;
      Oml[(zbase + (size_t)(trow + r) * NH + head) * 2 + 1] = lrow[r];
    }
  }
}

// ============================================================================
// 6-legacy) fallback attention reading f32 caches (used if ws too small)
// ============================================================================
__global__ __launch_bounds__(256) void attn_k(
    const u16* __restrict__ qbf, const float* __restrict__ outK,
    const float* __restrict__ outV, const int* __restrict__ clp,
    float* __restrict__ Opart, float* __restrict__ Oml)
{
  __shared__ u16 Ksl[32 * 136];
  __shared__ u16 Vtl[128 * 40];
  __shared__ u16 Psl[4 * 16 * 40];
  const int tid = threadIdx.x;
  const int lane = tid & 63, wave = tid >> 6;
  const int quad = lane >> 4, m16 = lane & 15;
  const int head = blockIdx.y;
  const int qbase = blockIdx.x * 64 + wave * 16;
  const int z = blockIdx.z, splits = gridDim.z;
  const int Svalid = *clp + TNEW;
  const int ntiles = (Svalid + 31) >> 5;
  const int per = (ntiles + splits - 1) / splits;
  const int it0 = z * per;
  const int it1 = min(ntiles, it0 + per);

  short8 qf[4];
#pragma unroll
  for (int kb = 0; kb < 4; kb++)
    qf[kb] = ldfrag(&qbf[((size_t)(qbase + m16) * NH + head) * HD + kb * 32 + quad * 8]);

  floatx4 O[8];
#pragma unroll
  for (int i = 0; i < 8; i++)
#pragma unroll
    for (int r = 0; r < 4; r++) O[i][r] = 0.0f;
  float mrow[4], lrow[4];
#pragma unroll
  for (int r = 0; r < 4; r++) { mrow[r] = -1e30f; lrow[r] = 0.0f; }

  const int sstage = tid >> 3;
  const int hg = (tid & 7) * 16;

  for (int it = it0; it < it1; it++) {
    const int s0 = it * 32;
    {
      int srow = s0 + sstage; if (srow > MAXKV - 1) srow = MAXKV - 1;
      const float* kp = outK + ((size_t)head * MAXKV + srow) * HD + hg;
      float tv[16];
      *(float4*)(tv)      = *(const float4*)(kp);
      *(float4*)(tv + 4)  = *(const float4*)(kp + 4);
      *(float4*)(tv + 8)  = *(const float4*)(kp + 8);
      *(float4*)(tv + 12) = *(const float4*)(kp + 12);
      *(uint4*)&Ksl[sstage * 136 + hg]     = pack8(tv);
      *(uint4*)&Ksl[sstage * 136 + hg + 8] = pack8(tv + 8);
      const float* vp = outV + ((size_t)head * MAXKV + srow) * HD + hg;
      float vv[16];
      *(float4*)(vv)      = *(const float4*)(vp);
      *(float4*)(vv + 4)  = *(const float4*)(vp + 4);
      *(float4*)(vv + 8)  = *(const float4*)(vp + 8);
      *(float4*)(vv + 12) = *(const float4*)(vp + 12);
#pragma unroll
      for (int j = 0; j < 16; j++) Vtl[(hg + j) * 40 + sstage] = f2bf(vv[j]);
    }
    __syncthreads();

    floatx4 sc[2];
#pragma unroll
    for (int st = 0; st < 2; st++) {
      floatx4 a;
#pragma unroll
      for (int r = 0; r < 4; r++) a[r] = 0.0f;
#pragma unroll
      for (int kb = 0; kb < 4; kb++) {
        short8 kf = ldfrag(&Ksl[(st * 16 + m16) * 136 + kb * 32 + quad * 8]);
        a = __builtin_amdgcn_mfma_f32_16x16x32_bf16(qf[kb], kf, a, 0, 0, 0);
      }
      const int scol = s0 + st * 16 + m16;
      if (scol >= Svalid) {
#pragma unroll
        for (int r = 0; r < 4; r++) a[r] = -1e30f;
      }
      sc[st] = a;
    }

    float alpha[4];
#pragma unroll
    for (int r = 0; r < 4; r++) {
      float mx = fmaxf(sc[0][r], sc[1][r]);
      mx = fmaxf(mx, __shfl_xor(mx, 1, 64));
      mx = fmaxf(mx, __shfl_xor(mx, 2, 64));
      mx = fmaxf(mx, __shfl_xor(mx, 4, 64));
      mx = fmaxf(mx, __shfl_xor(mx, 8, 64));
      const float mn = fmaxf(mrow[r], mx);
      alpha[r] = exp2f(mrow[r] - mn);
      const float p0 = exp2f(sc[0][r] - mn);
      const float p1 = exp2f(sc[1][r] - mn);
      sc[0][r] = p0; sc[1][r] = p1;
      float rs = p0 + p1;
      rs += __shfl_xor(rs, 1, 64);
      rs += __shfl_xor(rs, 2, 64);
      rs += __shfl_xor(rs, 4, 64);
      rs += __shfl_xor(rs, 8, 64);
      lrow[r] = lrow[r] * alpha[r] + rs;
      mrow[r] = mn;
    }
#pragma unroll
    for (int hb = 0; hb < 8; hb++)
#pragma unroll
      for (int r = 0; r < 4; r++) O[hb][r] *= alpha[r];

    u16* myPs = &Psl[wave * 640];
#pragma unroll
    for (int st = 0; st < 2; st++)
#pragma unroll
      for (int r = 0; r < 4; r++)
        myPs[(quad * 4 + r) * 40 + st * 16 + m16] = f2bf(sc[st][r]);
    short8 pf = ldfrag(&myPs[m16 * 40 + quad * 8]);
#pragma unroll
    for (int hb = 0; hb < 8; hb++) {
      short8 vf = ldfrag(&Vtl[(hb * 16 + m16) * 40 + quad * 8]);
      O[hb] = __builtin_amdgcn_mfma_f32_16x16x32_bf16(pf, vf, O[hb], 0, 0, 0);
    }
    __syncthreads();
  }

  const size_t zbase = (size_t)z * TN * NH;
  const int trow = qbase + quad * 4;
#pragma unroll
  for (int hb = 0; hb < 8; hb++)
#pragma unroll
    for (int r = 0; r < 4; r++)
      Opart[(zbase + (size_t)(trow + r) * NH + head) * HD + hb * 16 + m16] = O[hb][r];
  if (m16 == 0) {
#pragma unroll
    for (int r = 0; r < 4; r++) {
      Oml[(zbase + (size_t)(trow + r) * NH + head) * 2 + 0] = mrow[r];
      Oml[(zbase + (size_t)(trow + r) * NH + head) * 2 + 1] = lrow[r];
    }
  }
}

// ============================================================================
// 6b) combine split-S partials -> attnb (f32) and attnbf (bf16)
// ============================================================================
__global__ __launch_bounds__(128) void attn_combine(
    const float* __restrict__ Opart, const float* __restrict__ Oml,
    float* __restrict__ attnb, u16* __restrict__ attnbf, int splits)
{
  const int pair = blockIdx.x;   // t*NH + head
  const int h = threadIdx.x;
  float M = -1e30f;
  for (int zz = 0; zz < splits; zz++)
    M = fmaxf(M, Oml[((size_t)zz * TN * NH + pair) * 2]);
  float l = 0.0f, o = 0.0f;
  for (int zz = 0; zz < splits; zz++) {
    const float mi = Oml[((size_t)zz * TN * NH + pair) * 2];
    const float li = Oml[((size_t)zz * TN * NH + pair) * 2 + 1];
    const float w = exp2f(mi - M);
    l += li * w;
    o += Opart[((size_t)zz * TN * NH + pair) * HD + h] * w;
  }
  const float res = o / l;
  attnb[(size_t)pair * HD + h] = res;
  if (attnbf) attnbf[(size_t)pair * HD + h] = f2bf(res);
}

// ============================================================================
// launch
// ============================================================================
extern "C" void kernel_launch(void* const* d_in, const int* in_sizes, int n_in,
                              void* d_out, int out_size, void* d_ws, size_t ws_size,
                              hipStream_t stream) {
  const float* x_noise       = (const float*)d_in[0];
  const float* target_hidden = (const float*)d_in[1];
  const int*   noise_pos     = (const int*)d_in[2];
  const int*   ctx_pos       = (const int*)d_in[3];
  const float* inK           = (const float*)d_in[4];
  const float* inV           = (const float*)d_in[5];
  const int*   cache_len     = (const int*)d_in[6];
  const float* wq            = (const float*)d_in[7];
  const float* wk            = (const float*)d_in[8];
  const float* wv            = (const float*)d_in[9];
  const float* wo            = (const float*)d_in[10];
  const float* q_scale       = (const float*)d_in[11];
  const float* k_scale       = (const float*)d_in[12];

  float* out0 = (float*)d_out;
  float* outK = out0 + (size_t)TN * HIDDEN;
  float* outV = outK + (size_t)NH * MAXKV * HD;

  // ---- workspace layout ----
  size_t off = 0;
  auto walloc = [&](size_t bytes) -> void* {
    void* p = (char*)d_ws + off;
    off += (bytes + 255) & ~(size_t)255;
    return p;
  };
  u16*   qbf    = (u16*)walloc((size_t)TN * HIDDEN * 2);
  float* attnb  = (float*)walloc((size_t)TN * HIDDEN * 4);
  u16*   attnbf = (u16*)walloc((size_t)TN * HIDDEN * 2);
  float* qproj  = (float*)walloc((size_t)TN * HIDDEN * 4);
  float* kproj  = (float*)walloc((size_t)TNEW * NKV * HD * 4);
  float* vproj  = (float*)walloc((size_t)TNEW * NKV * HD * 4);

  const size_t PER_SPLIT = (size_t)TN * NH * HD * 4 + (size_t)TN * NH * 8;
  const size_t SHB   = (size_t)NH * MAXKV * HD * sizeof(u16);   // 32 MB each
  const size_t GPART = (size_t)4 * TN * HIDDEN * 4;             // 16 MB
  const size_t CONVB = ((size_t)TN * HIDDEN + (size_t)TC * HIDDEN) * 2
                     + ((size_t)HIDDEN * HIDDEN * 2
                      + (size_t)HIDDEN * (NKV * HD) * 2) * 2;
  auto maxsz = [](size_t a, size_t b) { return a > b ? a : b; };

  size_t avail = (ws_size > off) ? ws_size - off : 0;
  bool conv = false;
  int asplits = 0;
  if (avail >= CONVB + 2 * SHB + maxsz(8 * PER_SPLIT, GPART))      { conv = true; asplits = 8; }
  else if (avail >= CONVB + 2 * SHB + maxsz(4 * PER_SPLIT, GPART)) { conv = true; asplits = 4; }
  else if (avail >= 2 * SHB + maxsz(8 * PER_SPLIT, GPART))         { asplits = 8; }
  else if (avail >= 2 * SHB + maxsz(4 * PER_SPLIT, GPART))         { asplits = 4; }
  const bool shadow = (asplits > 0);

  u16 *xbf = nullptr, *thbf = nullptr, *wqT = nullptr, *wkT = nullptr,
      *wvT = nullptr, *woT = nullptr;
  if (conv) {
    xbf  = (u16*)walloc((size_t)TN * HIDDEN * 2);
    thbf = (u16*)walloc((size_t)TC * HIDDEN * 2);
    wqT  = (u16*)walloc((size_t)HIDDEN * HIDDEN * 2);
    wkT  = (u16*)walloc((size_t)HIDDEN * (NKV * HD) * 2);
    wvT  = (u16*)walloc((size_t)HIDDEN * (NKV * HD) * 2);
    woT  = (u16*)walloc((size_t)HIDDEN * HIDDEN * 2);
  }
  u16 *Kb = nullptr, *VbT = nullptr;
  if (shadow) {
    Kb  = (u16*)walloc(SHB);
    VbT = (u16*)walloc(SHB);
  }

  float* scratch = (float*)((char*)d_ws + off);
  const size_t avail2 = (ws_size > off) ? ws_size - off : 0;
  if (!shadow) {
    asplits = 2;
    if (avail2 >= 8 * PER_SPLIT) asplits = 8;
    else if (avail2 >= 4 * PER_SPLIT) asplits = 4;
  }
  float* Opart = scratch;
  float* Oml   = Opart + (size_t)asplits * TN * NH * HD;
  const bool ksplit = (avail2 >= GPART);
  float* gpart = scratch;   // shared with Opart (phases don't overlap)

  if (conv) {
    conv_bf16<<<dim3((TN * HIDDEN / 4 + 255) / 256), dim3(256), 0, stream>>>(
        (const float4*)x_noise, (uint2*)xbf, TN * HIDDEN / 4);
    conv_bf16<<<dim3((TC * HIDDEN / 4 + 255) / 256), dim3(256), 0, stream>>>(
        (const float4*)target_hidden, (uint2*)thbf, TC * HIDDEN / 4);
    transpose_bf16<<<dim3(HIDDEN / 64, HIDDEN / 64), dim3(256), 0, stream>>>(
        wq, wqT, HIDDEN, HIDDEN);
    transpose_bf16<<<dim3(NKV * HD / 64, HIDDEN / 64), dim3(256), 0, stream>>>(
        wk, wkT, HIDDEN, NKV * HD);
    transpose_bf16<<<dim3(NKV * HD / 64, HIDDEN / 64), dim3(256), 0, stream>>>(
        wv, wvT, HIDDEN, NKV * HD);
    transpose_bf16<<<dim3(HIDDEN / 64, HIDDEN / 64), dim3(256), 0, stream>>>(
        wo, woT, NH * HD, HIDDEN);
  }

  cache_copy<<<dim3(32768), dim3(256), 0, stream>>>(
      (const float4*)inK, (const float4*)inV, (float4*)outK, (float4*)outV,
      cache_len, Kb);

  // Q projection (BM=64, BN=128 tiles)
  if (conv && ksplit) {
    gemm_v2<<<dim3(HIDDEN / 128, TN / 64, 4), dim3(256), 0, stream>>>(
        xbf, TN, xbf, wqT, wqT, HIDDEN, gpart, gpart, TN, HIDDEN, HIDDEN, 16);
    reduce4<<<dim3((TN * HIDDEN / 4 + 255) / 256), dim3(256), 0, stream>>>(
        (const float4*)gpart, (float4*)qproj, TN * HIDDEN / 4);
  } else if (conv) {
    gemm_v2<<<dim3(HIDDEN / 128, TN / 64, 1), dim3(256), 0, stream>>>(
        xbf, TN, xbf, wqT, wqT, HIDDEN, qproj, qproj, TN, HIDDEN, HIDDEN, 64);
  } else if (ksplit) {
    gemm_bf16<<<dim3(HIDDEN / 64, TN / 64, 4), dim3(256), 0, stream>>>(
        x_noise, TN, x_noise, wq, wq, HIDDEN, gpart, gpart, TN, HIDDEN, HIDDEN, 16);
    reduce4<<<dim3((TN * HIDDEN / 4 + 255) / 256), dim3(256), 0, stream>>>(
        (const float4*)gpart, (float4*)qproj, TN * HIDDEN / 4);
  } else {
    gemm_bf16<<<dim3(HIDDEN / 64, TN / 64, 1), dim3(256), 0, stream>>>(
        x_noise, TN, x_noise, wq, wq, HIDDEN, qproj, qproj, TN, HIDDEN, HIDDEN, 64);
  }

  // merged K+V projection
  if (conv) {
    gemm_v2<<<dim3(2 * NKV * HD / 128, TNEW / 64, 1), dim3(256), 0, stream>>>(
        thbf, TC, xbf, wkT, wvT, NKV * HD, kproj, vproj,
        TNEW, 2 * NKV * HD, HIDDEN, 64);
  } else {
    gemm_bf16<<<dim3(2 * NKV * HD / 64, TNEW / 64, 1), dim3(256), 0, stream>>>(
        target_hidden, TC, x_noise, wk, wv, NKV * HD, kproj, vproj,
        TNEW, 2 * NKV * HD, HIDDEN, 64);
  }

  q_post_k<<<dim3(TN, NH), dim3(64), 0, stream>>>(qproj, noise_pos, q_scale, qbf);
  k_post_k<<<dim3(TNEW, NKV), dim3(64), 0, stream>>>(
      kproj, ctx_pos, noise_pos, k_scale, cache_len, outK, Kb);
  v_post_k<<<dim3(TNEW, NKV), dim3(128), 0, stream>>>(vproj, cache_len, outV);
  if (shadow) {
    vT_build<<<dim3(MAXKV / 64, HD / 64, NH), dim3(256), 0, stream>>>(
        inV, vproj, cache_len, VbT);
  }

  if (shadow) {
    attn_sh<<<dim3((TN / 64) * NH * asplits), dim3(256), 0, stream>>>(
        qbf, Kb, VbT, cache_len, Opart, Oml, asplits);
  } else {
    attn_k<<<dim3(TN / 64, NH, asplits), dim3(256), 0, stream>>>(
        qbf, outK, outV, cache_len, Opart, Oml);
  }
  attn_combine<<<dim3(TN * NH), dim3(128), 0, stream>>>(
      Opart, Oml, attnb, conv ? attnbf : nullptr, asplits);

  // output projection
  if (conv && ksplit) {
    gemm_v2<<<dim3(HIDDEN / 128, TN / 64, 4), dim3(256), 0, stream>>>(
        attnbf, TN, attnbf, woT, woT, HIDDEN, gpart, gpart, TN, HIDDEN, HIDDEN, 16);
    reduce4<<<dim3((TN * HIDDEN / 4 + 255) / 256), dim3(256), 0, stream>>>(
        (const float4*)gpart, (float4*)out0, TN * HIDDEN / 4);
  } else if (conv) {
    gemm_v2<<<dim3(HIDDEN / 128, TN / 64, 1), dim3(256), 0, stream>>>(
        attnbf, TN, attnbf, woT, woT, HIDDEN, out0, out0, TN, HIDDEN, HIDDEN, 64);
  } else if (ksplit) {
    gemm_bf16<<<dim3(HIDDEN / 64, TN / 64, 4), dim3(256), 0, stream>>>(
        attnb, TN, attnb, wo, wo, HIDDEN, gpart, gpart, TN, HIDDEN, HIDDEN, 16);
    reduce4<<<dim3((TN * HIDDEN / 4 + 255) / 256), dim3(256), 0, stream>>>(
        (const float4*)gpart, (float4*)out0, TN * HIDDEN / 4);
  } else {
    gemm_bf16<<<dim3(HIDDEN / 64, TN / 64, 1), dim3(256), 0, stream>>>(
        attnb, TN, attnb, wo, wo, HIDDEN, out0, out0, TN, HIDDEN, HIDDEN, 64);
  }
}